// Round 4
// baseline (454.324 us; speedup 1.0000x reference)
//
#include <hip/hip_runtime.h>

#define BN_EPS 1e-5f

using h8 = __attribute__((ext_vector_type(8))) _Float16;
using f4v = __attribute__((ext_vector_type(4))) float;

__device__ __forceinline__ float elu_f(float x) {
    return x > 0.f ? x : __expf(x) - 1.f;
}

__device__ __forceinline__ unsigned short bf16r(float x) {
    unsigned u = __float_as_uint(x);
    return (unsigned short)((u + 0x7fffu + ((u >> 16) & 1u)) >> 16);
}

// ---------------------------------------------------------------------------
// fp32 tile GEMM helpers (node-level kernels).
// ---------------------------------------------------------------------------

__device__ __forceinline__ void gemm_acc(float acc[4][8], float a0, float a1, float a2,
                                         float a3, const float4 wa, const float4 wb) {
    const float w[8] = {wa.x, wa.y, wa.z, wa.w, wb.x, wb.y, wb.z, wb.w};
    const float a[4] = {a0, a1, a2, a3};
#pragma unroll
    for (int j = 0; j < 4; ++j)
#pragma unroll
        for (int u = 0; u < 8; ++u)
            acc[j][u] = fmaf(a[j], w[u], acc[j][u]);
}

__device__ __forceinline__ void gemm_globalW(const float* As, int lda,
                                             const float* __restrict__ Wg, int K,
                                             float acc[4][8], int tx, int ty) {
    const float4* Wg4 = (const float4*)Wg;
#pragma unroll 4
    for (int k = 0; k < K; ++k) {
        float a0 = As[ty * lda + k];
        float a1 = As[(ty + 16) * lda + k];
        float a2 = As[(ty + 32) * lda + k];
        float a3 = As[(ty + 48) * lda + k];
        float4 wa = Wg4[k * 32 + tx];
        float4 wb = Wg4[k * 32 + 16 + tx];
        gemm_acc(acc, a0, a1, a2, a3, wa, wb);
    }
}

__device__ __forceinline__ void bias_elu(const float acc[4][8], const float* __restrict__ bias,
                                         float vals[4][8], int tx) {
    int ca = 4 * tx, cb = 64 + 4 * tx;
    float bv[8] = {bias[ca], bias[ca + 1], bias[ca + 2], bias[ca + 3],
                   bias[cb], bias[cb + 1], bias[cb + 2], bias[cb + 3]};
#pragma unroll
    for (int j = 0; j < 4; ++j)
#pragma unroll
        for (int u = 0; u < 8; ++u)
            vals[j][u] = elu_f(acc[j][u] + bv[u]);
}

__device__ __forceinline__ void store_tile(float* __restrict__ out, int row0,
                                           const float vals[4][8], int tx, int ty) {
#pragma unroll
    for (int j = 0; j < 4; ++j) {
        int r = row0 + ty + 16 * j;
        *(float4*)(out + r * 128 + 4 * tx) =
            make_float4(vals[j][0], vals[j][1], vals[j][2], vals[j][3]);
        *(float4*)(out + r * 128 + 64 + 4 * tx) =
            make_float4(vals[j][4], vals[j][5], vals[j][6], vals[j][7]);
    }
}

__device__ __forceinline__ void stats_tail(const float vals[4][8], float* red,
                                           float* __restrict__ st, int tid, int tx, int ty) {
    float ls[8], lq[8];
#pragma unroll
    for (int u = 0; u < 8; ++u) {
        ls[u] = vals[0][u] + vals[1][u] + vals[2][u] + vals[3][u];
        lq[u] = vals[0][u] * vals[0][u] + vals[1][u] * vals[1][u] +
                vals[2][u] * vals[2][u] + vals[3][u] * vals[3][u];
    }
    __syncthreads();
    int ca = 4 * tx, cb = 64 + 4 * tx;
#pragma unroll
    for (int u = 0; u < 4; ++u) {
        red[ty * 128 + ca + u] = ls[u];
        red[2048 + ty * 128 + ca + u] = lq[u];
        red[ty * 128 + cb + u] = ls[u + 4];
        red[2048 + ty * 128 + cb + u] = lq[u + 4];
    }
    __syncthreads();
    if (tid < 128) {
        float s = 0.f, q = 0.f;
#pragma unroll
        for (int t = 0; t < 16; ++t) {
            s += red[t * 128 + tid];
            q += red[2048 + t * 128 + tid];
        }
        atomicAdd(st + tid, s);
        atomicAdd(st + 128 + tid, q);
    }
}

// ---------------------------------------------------------------------------
// MFMA helpers. A-frag LDS layout: Afr[((rt*4+kc)*64 + o*16 + m)*8 + j] =
// act[rt*16+m][kc*32+o*8+j] (fp16). Weights prepacked in GLOBAL with the same
// unit layout: Wp[((ct*4+kc)*64 + L)*8 + j] = W[kc*32+(L>>4)*8+j][ct*16+(L&15)].
// Wave w computes rows 0..63 x cols [32w, 32w+32); B-frags are read directly
// from global (coalesced 16B/lane, L1/L2-hot: same 32KB for all blocks).
// ---------------------------------------------------------------------------

__device__ __forceinline__ void mfma_gemm_gw(const _Float16* Afr,
                                             const _Float16* __restrict__ wp,
                                             f4v acc[4][2], int lane, int w) {
#pragma unroll
    for (int kc = 0; kc < 4; ++kc) {
        h8 bf0 = *(const h8*)&wp[(((w * 2 + 0) * 4 + kc) * 64 + lane) * 8];
        h8 bf1 = *(const h8*)&wp[(((w * 2 + 1) * 4 + kc) * 64 + lane) * 8];
        h8 af[4];
#pragma unroll
        for (int rt = 0; rt < 4; ++rt)
            af[rt] = *(const h8*)&Afr[((rt * 4 + kc) * 64 + lane) * 8];
#pragma unroll
        for (int rt = 0; rt < 4; ++rt)
            acc[rt][0] = __builtin_amdgcn_mfma_f32_16x16x32_f16(af[rt], bf0, acc[rt][0], 0, 0, 0);
#pragma unroll
        for (int rt = 0; rt < 4; ++rt)
            acc[rt][1] = __builtin_amdgcn_mfma_f32_16x16x32_f16(af[rt], bf1, acc[rt][1], 0, 0, 0);
    }
}

// write fp32 vals (C-layout) back into A-frag fp16 LDS layout
__device__ __forceinline__ void vals_to_afrag(_Float16* Afr, const float vals[4][2][4],
                                              int lane, int w) {
    int cl = lane & 15, quad = lane >> 4;
#pragma unroll
    for (int ctl = 0; ctl < 2; ++ctl) {
        int col = (w * 2 + ctl) * 16 + cl;
        int kc = col >> 5, o = (col >> 3) & 3, j = col & 7;
#pragma unroll
        for (int rt = 0; rt < 4; ++rt)
#pragma unroll
            for (int i = 0; i < 4; ++i) {
                int m = quad * 4 + i;
                Afr[((rt * 4 + kc) * 64 + o * 16 + m) * 8 + j] = (_Float16)vals[rt][ctl][i];
            }
    }
}

// ---------------------------------------------------------------------------
// Kernels
// ---------------------------------------------------------------------------

__global__ void k_zero(float* w) {
    int i = blockIdx.x * 256 + threadIdx.x;
    if (i < 2176) w[i] = 0.f;  // 4x512 stats + 128 cvec
}

// stats layout per stage: [0:128) sum, [128:256) sumsq, [256:384) a, [384:512) shift
__global__ void k_finalize(float* st, float invM, const float* __restrict__ g,
                           const float* __restrict__ beta) {
    int c = threadIdx.x;
    float mean = st[c] * invM;
    float var = st[128 + c] * invM - mean * mean;
    float a = g[c] * rsqrtf(var + BN_EPS);
    st[256 + c] = a;
    st[384 + c] = beta[c] - mean * a;
}

// pack fp32 W[128][128] (row-major k x col) into MFMA-B fp16 frag layout
__global__ void k_packw(const float* __restrict__ w, _Float16* __restrict__ wp) {
    int flat = blockIdx.x * 256 + threadIdx.x;  // 0..2047
    int g = flat >> 6, L = flat & 63;
    int ct = g >> 2, kc = g & 3;
    int n = ct * 16 + (L & 15), k0 = kc * 32 + (L >> 4) * 8;
    h8 v;
#pragma unroll
    for (int j = 0; j < 8; ++j) v[j] = (_Float16)w[(k0 + j) * 128 + n];
    *(h8*)&wp[flat * 8] = v;
}

// mlp1: rows = B*N = 4096, K1 = 40 (transposed gather of inputs), K2 = 128. fp32.
__global__ __launch_bounds__(256) void k_mlp1(const float* __restrict__ x,
                                              const float* __restrict__ w1,
                                              const float* __restrict__ b1,
                                              const float* __restrict__ w2,
                                              const float* __restrict__ b2,
                                              float* __restrict__ h1, float* __restrict__ st) {
    __shared__ float Xs[64 * 44];
    __shared__ float As[64 * 132];
    int tid = threadIdx.x, tx = tid & 15, ty = tid >> 4;
    int r0 = blockIdx.x * 64;
    for (int idx = tid; idx < 64 * 40; idx += 256) {
        int r = idx / 40, k = idx - r * 40;
        int rr = r0 + r, b = rr >> 6, n = rr & 63, t = k >> 2, d = k & 3;
        Xs[r * 44 + k] = x[((b * 10 + t) * 64 + n) * 4 + d];
    }
    __syncthreads();
    float acc[4][8] = {};
    gemm_globalW(Xs, 44, w1, 40, acc, tx, ty);
    float vals[4][8];
    bias_elu(acc, b1, vals, tx);
    int ca = 4 * tx, cb = 64 + 4 * tx;
#pragma unroll
    for (int j = 0; j < 4; ++j) {
        int r = ty + 16 * j;
#pragma unroll
        for (int u = 0; u < 4; ++u) {
            As[r * 132 + ca + u] = vals[j][u];
            As[r * 132 + cb + u] = vals[j][u + 4];
        }
    }
    __syncthreads();
    float acc2[4][8] = {};
    gemm_globalW(As, 132, w2, 128, acc2, tx, ty);
    float vals2[4][8];
    bias_elu(acc2, b2, vals2, tx);
    store_tile(h1, r0, vals2, tx, ty);
    stats_tail(vals2, As, st, tid, tx, ty);
}

// P/Q precompute: P = BN(h) @ W[0:128], Q = BN(h) @ W[128:256]. fp32, 128 blocks.
__global__ __launch_bounds__(256) void k_pq(const float* __restrict__ h,
                                            const float* __restrict__ st,
                                            const float* __restrict__ w,
                                            float* __restrict__ P, float* __restrict__ Q) {
    __shared__ float As[64 * 132];
    int tid = threadIdx.x, tx = tid & 15, ty = tid >> 4;
    int half = blockIdx.x >> 6;
    int r0 = (blockIdx.x & 63) * 64;
    const float* Wg = w + half * 128 * 128;
    float* out = half ? Q : P;
    const float4* h4 = (const float4*)h;
    const float4* av = (const float4*)(st + 256);
    const float4* cv = (const float4*)(st + 384);
#pragma unroll
    for (int i = 0; i < 8; ++i) {
        int f4 = tid + i * 256;
        int r = f4 >> 5, c4 = f4 & 31;
        float4 hv = h4[(r0 + r) * 32 + c4];
        float4 a = av[c4], c = cv[c4];
        float4 v;
        v.x = a.x * hv.x + c.x;
        v.y = a.y * hv.y + c.y;
        v.z = a.z * hv.z + c.z;
        v.w = a.w * hv.w + c.w;
        *(float4*)(As + r * 132 + c4 * 4) = v;
    }
    __syncthreads();
    float acc[4][8] = {};
    gemm_globalW(As, 132, Wg, 128, acc, tx, ty);
#pragma unroll
    for (int j = 0; j < 4; ++j) {
        int r = r0 + ty + 16 * j;
        *(float4*)(out + r * 128 + 4 * tx) = make_float4(acc[j][0], acc[j][1], acc[j][2], acc[j][3]);
        *(float4*)(out + r * 128 + 64 + 4 * tx) = make_float4(acc[j][4], acc[j][5], acc[j][6], acc[j][7]);
    }
}

// Recv-major fused mlp2 + edge2node (MFMA, weights from global). One block per
// (b, recv n); rows = 63 real edges + dummy row 63. h2 never stored.
__global__ __launch_bounds__(256, 4) void k_mlp2agg(const float* __restrict__ P2,
                                                    const float* __restrict__ Q2,
                                                    const float* __restrict__ b1,
                                                    const _Float16* __restrict__ w2p,
                                                    const float* __restrict__ b2,
                                                    float* __restrict__ aggraw,
                                                    float* __restrict__ st) {
    __shared__ _Float16 Afr[8192];  // 16 KB
    int tid = threadIdx.x;
    int lane = tid & 63, w = tid >> 6;
    int b = blockIdx.x >> 6, n = blockIdx.x & 63;
    {  // elementwise: r = lane, kc = w
        int r = lane, kc = w;
        int s = (r < 63) ? (r + (r >= n ? 1 : 0)) : n;
        const float4* Pr = (const float4*)(P2 + (b * 64 + s) * 128);
        const float4* Qr = (const float4*)(Q2 + (b * 64 + n) * 128);
        const float4* B1 = (const float4*)b1;
        int rt = r >> 4, m = r & 15;
#pragma unroll
        for (int o = 0; o < 4; ++o) {
            int c4 = kc * 8 + o * 2;
            float4 p0 = Pr[c4], q0 = Qr[c4], bb0 = B1[c4];
            float4 p1 = Pr[c4 + 1], q1 = Qr[c4 + 1], bb1 = B1[c4 + 1];
            h8 v;
            v[0] = (_Float16)elu_f(p0.x + q0.x + bb0.x);
            v[1] = (_Float16)elu_f(p0.y + q0.y + bb0.y);
            v[2] = (_Float16)elu_f(p0.z + q0.z + bb0.z);
            v[3] = (_Float16)elu_f(p0.w + q0.w + bb0.w);
            v[4] = (_Float16)elu_f(p1.x + q1.x + bb1.x);
            v[5] = (_Float16)elu_f(p1.y + q1.y + bb1.y);
            v[6] = (_Float16)elu_f(p1.z + q1.z + bb1.z);
            v[7] = (_Float16)elu_f(p1.w + q1.w + bb1.w);
            *(h8*)&Afr[((rt * 4 + kc) * 64 + o * 16 + m) * 8] = v;
        }
    }
    __syncthreads();
    f4v acc[4][2];
#pragma unroll
    for (int rt = 0; rt < 4; ++rt)
#pragma unroll
        for (int c = 0; c < 2; ++c) acc[rt][c] = (f4v){0.f, 0.f, 0.f, 0.f};
    mfma_gemm_gw(Afr, w2p, acc, lane, w);
    // epilogue: bias+elu, mask dummy row 63, wave-complete column reduce
    int cl = lane & 15, quad = lane >> 4;
#pragma unroll
    for (int ctl = 0; ctl < 2; ++ctl) {
        int col = (w * 2 + ctl) * 16 + cl;
        float bias = b2[col];
        float s1 = 0.f, s2 = 0.f;
#pragma unroll
        for (int rt = 0; rt < 4; ++rt)
#pragma unroll
            for (int i = 0; i < 4; ++i) {
                int row = rt * 16 + quad * 4 + i;
                float v = elu_f(acc[rt][ctl][i] + bias);
                if (row == 63) v = 0.f;
                s1 += v;
                s2 += v * v;
            }
        s1 += __shfl_xor(s1, 16);
        s2 += __shfl_xor(s2, 16);
        s1 += __shfl_xor(s1, 32);
        s2 += __shfl_xor(s2, 32);
        if (quad == 0) {
            aggraw[(b * 64 + n) * 128 + col] = s1;
            atomicAdd(st + col, s1);
            atomicAdd(st + 128 + col, s2);
        }
    }
}

// prep for mlp4 skip path: wcp (fp16, MFMA-B layout) = a2[k]*W4_1[256+k][c];
// cvec[c] += shift2[k]*W4_1[256+k][c]
__global__ void k_wcprep(const float* __restrict__ w41, const float* __restrict__ st2,
                         _Float16* __restrict__ wcp, float* __restrict__ cvec) {
    int k = blockIdx.x, c = threadIdx.x;  // 128 x 128
    float wv = w41[(256 + k) * 128 + c];
    int g = (c >> 4) * 4 + (k >> 5);
    int L = ((k >> 3) & 3) * 16 + (c & 15);
    int j = k & 7;
    wcp[(g * 64 + L) * 8 + j] = (_Float16)(st2[256 + k] * wv);
    atomicAdd(&cvec[c], st2[384 + k] * wv);
}

// mlp3: rows = 4096, input = a2*(aggraw/63)+shift2, K=128 both layers. fp32.
__global__ __launch_bounds__(256) void k_mlp3(const float* __restrict__ raw,
                                              const float* __restrict__ st2,
                                              const float* __restrict__ w1,
                                              const float* __restrict__ b1,
                                              const float* __restrict__ w2,
                                              const float* __restrict__ b2,
                                              float* __restrict__ h3, float* __restrict__ st) {
    __shared__ float As[64 * 132];
    int tid = threadIdx.x, tx = tid & 15, ty = tid >> 4;
    int r0 = blockIdx.x * 64;
    const float4* in4 = (const float4*)raw;
    const float4* av = (const float4*)(st2 + 256);
    const float4* cv = (const float4*)(st2 + 384);
    const float inv63 = 1.f / 63.f;
#pragma unroll
    for (int i = 0; i < 8; ++i) {
        int f4 = tid + i * 256;
        int r = f4 >> 5, c4 = f4 & 31;
        float4 hv = in4[(r0 + r) * 32 + c4];
        float4 a = av[c4], c = cv[c4];
        float4 v;
        v.x = a.x * hv.x * inv63 + c.x;
        v.y = a.y * hv.y * inv63 + c.y;
        v.z = a.z * hv.z * inv63 + c.z;
        v.w = a.w * hv.w * inv63 + c.w;
        *(float4*)(As + r * 132 + c4 * 4) = v;
    }
    __syncthreads();
    float acc[4][8] = {};
    gemm_globalW(As, 132, w1, 128, acc, tx, ty);
    float vals[4][8];
    bias_elu(acc, b1, vals, tx);
    __syncthreads();
    int ca = 4 * tx, cb = 64 + 4 * tx;
#pragma unroll
    for (int j = 0; j < 4; ++j) {
        int r = ty + 16 * j;
#pragma unroll
        for (int u = 0; u < 4; ++u) {
            As[r * 132 + ca + u] = vals[j][u];
            As[r * 132 + cb + u] = vals[j][u + 4];
        }
    }
    __syncthreads();
    float acc2[4][8] = {};
    gemm_globalW(As, 132, w2, 128, acc2, tx, ty);
    float vals2[4][8];
    bias_elu(acc2, b2, vals2, tx);
    store_tile(h3, r0, vals2, tx, ty);
    stats_tail(vals2, As, st, tid, tx, ty);
}

// mlp4 edge kernel (MFMA, send-major tiles, weights from global).
// GEMM1 recomputes h2 from P2/Q2, GEMM2 = skip path h2 @ Wc', GEMM3 = mlp4
// layer 2. Stores h4 bf16 + stats.
__global__ __launch_bounds__(256, 4) void k_mlp4r(const float* __restrict__ P2,
                                                  const float* __restrict__ Q2,
                                                  const float* __restrict__ m2b1,
                                                  const _Float16* __restrict__ w2p2,
                                                  const float* __restrict__ m2b2,
                                                  const float* __restrict__ P4,
                                                  const float* __restrict__ Q4,
                                                  const _Float16* __restrict__ wcp,
                                                  const float* __restrict__ cvec,
                                                  const float* __restrict__ b1,
                                                  const _Float16* __restrict__ w4p2,
                                                  const float* __restrict__ b2,
                                                  unsigned short* __restrict__ h4,
                                                  float* __restrict__ st) {
    __shared__ _Float16 Afr[8192];  // 16 KB (also reused as bf16 bounce tile)
    int tid = threadIdx.x;
    int lane = tid & 63, w = tid >> 6;
    unsigned blk = blockIdx.x;
    unsigned b = blk / 63;
    unsigned e0 = (blk - b * 63) * 64;
    int row0 = blk * 64;
    int cl = lane & 15, quad = lane >> 4;
    {  // elementwise A_skip = elu(P2[s]+Q2[rv]+m2b1): r = lane, kc = w
        int r = lane, kc = w;
        unsigned e = e0 + r;
        unsigned s = e / 63;
        unsigned jj = e - s * 63;
        unsigned rv = jj + (jj >= s ? 1u : 0u);
        const float4* Pr = (const float4*)(P2 + (b * 64 + s) * 128);
        const float4* Qr = (const float4*)(Q2 + (b * 64 + rv) * 128);
        const float4* B1 = (const float4*)m2b1;
        int rt = r >> 4, m = r & 15;
#pragma unroll
        for (int o = 0; o < 4; ++o) {
            int c4 = kc * 8 + o * 2;
            float4 p0 = Pr[c4], q0 = Qr[c4], bb0 = B1[c4];
            float4 p1 = Pr[c4 + 1], q1 = Qr[c4 + 1], bb1 = B1[c4 + 1];
            h8 v;
            v[0] = (_Float16)elu_f(p0.x + q0.x + bb0.x);
            v[1] = (_Float16)elu_f(p0.y + q0.y + bb0.y);
            v[2] = (_Float16)elu_f(p0.z + q0.z + bb0.z);
            v[3] = (_Float16)elu_f(p0.w + q0.w + bb0.w);
            v[4] = (_Float16)elu_f(p1.x + q1.x + bb1.x);
            v[5] = (_Float16)elu_f(p1.y + q1.y + bb1.y);
            v[6] = (_Float16)elu_f(p1.z + q1.z + bb1.z);
            v[7] = (_Float16)elu_f(p1.w + q1.w + bb1.w);
            *(h8*)&Afr[((rt * 4 + kc) * 64 + o * 16 + m) * 8] = v;
        }
    }
    __syncthreads();
    f4v acc[4][2];
#pragma unroll
    for (int rt = 0; rt < 4; ++rt)
#pragma unroll
        for (int c = 0; c < 2; ++c) acc[rt][c] = (f4v){0.f, 0.f, 0.f, 0.f};
    mfma_gemm_gw(Afr, w2p2, acc, lane, w);
    // epilogue 1: h2 = elu(acc + m2b2[col])
    float vals[4][2][4];
#pragma unroll
    for (int ctl = 0; ctl < 2; ++ctl) {
        float bias = m2b2[(w * 2 + ctl) * 16 + cl];
#pragma unroll
        for (int rt = 0; rt < 4; ++rt)
#pragma unroll
            for (int i = 0; i < 4; ++i)
                vals[rt][ctl][i] = elu_f(acc[rt][ctl][i] + bias);
    }
    __syncthreads();
    vals_to_afrag(Afr, vals, lane, w);
    __syncthreads();
#pragma unroll
    for (int rt = 0; rt < 4; ++rt)
#pragma unroll
        for (int c = 0; c < 2; ++c) acc[rt][c] = (f4v){0.f, 0.f, 0.f, 0.f};
    mfma_gemm_gw(Afr, wcp, acc, lane, w);
    // epilogue 2: pre1 = acc + P4[s][col] + Q4[rv][col] + b1[col] + cvec[col] -> elu
#pragma unroll
    for (int ctl = 0; ctl < 2; ++ctl) {
        int col = (w * 2 + ctl) * 16 + cl;
        float base = b1[col] + cvec[col];
#pragma unroll
        for (int rt = 0; rt < 4; ++rt)
#pragma unroll
            for (int i = 0; i < 4; ++i) {
                unsigned e = e0 + rt * 16 + quad * 4 + i;
                unsigned s = e / 63;
                unsigned jj = e - s * 63;
                unsigned rv = jj + (jj >= s ? 1u : 0u);
                float p = P4[(b * 64 + s) * 128 + col];
                float q = Q4[(b * 64 + rv) * 128 + col];
                vals[rt][ctl][i] = elu_f(acc[rt][ctl][i] + p + q + base);
            }
    }
    __syncthreads();
    vals_to_afrag(Afr, vals, lane, w);
    __syncthreads();
#pragma unroll
    for (int rt = 0; rt < 4; ++rt)
#pragma unroll
        for (int c = 0; c < 2; ++c) acc[rt][c] = (f4v){0.f, 0.f, 0.f, 0.f};
    mfma_gemm_gw(Afr, w4p2, acc, lane, w);
    // epilogue 3: h4 = elu(acc + b2[col]); stats; bf16 store via LDS bounce
    unsigned short* Tile = (unsigned short*)Afr;
#pragma unroll
    for (int ctl = 0; ctl < 2; ++ctl) {
        int col = (w * 2 + ctl) * 16 + cl;
        float bias = b2[col];
        float s1 = 0.f, s2 = 0.f;
#pragma unroll
        for (int rt = 0; rt < 4; ++rt)
#pragma unroll
            for (int i = 0; i < 4; ++i) {
                float v = elu_f(acc[rt][ctl][i] + bias);
                vals[rt][ctl][i] = v;
                s1 += v;
                s2 += v * v;
            }
        s1 += __shfl_xor(s1, 16);
        s2 += __shfl_xor(s2, 16);
        s1 += __shfl_xor(s1, 32);
        s2 += __shfl_xor(s2, 32);
        if (quad == 0) {
            atomicAdd(st + col, s1);
            atomicAdd(st + 128 + col, s2);
        }
    }
    __syncthreads();  // A-frag reads of GEMM3 complete; reuse Afr as bf16 tile
#pragma unroll
    for (int ctl = 0; ctl < 2; ++ctl) {
        int col = (w * 2 + ctl) * 16 + cl;
#pragma unroll
        for (int rt = 0; rt < 4; ++rt)
#pragma unroll
            for (int i = 0; i < 4; ++i)
                Tile[(rt * 16 + quad * 4 + i) * 128 + col] = bf16r(vals[rt][ctl][i]);
    }
    __syncthreads();
    {  // coalesced bf16 store: thread -> row tid>>2, 32-col quarter tid&3
        int r = tid >> 2, cq = tid & 3;
#pragma unroll
        for (int i = 0; i < 4; ++i) {
            int off = r * 128 + cq * 32 + i * 8;
            *(uint4*)(h4 + (size_t)row0 * 128 + off) = *(uint4*)&Tile[off];
        }
    }
}

// final: out[row,k] = sum_c (a4[c]*h4[row,c]+shift4[c]) * fcw[c,k] + fcb[k]
__global__ __launch_bounds__(256) void k_out(const unsigned short* __restrict__ h4,
                                             const float* __restrict__ st4,
                                             const float* __restrict__ fcw,
                                             const float* __restrict__ fcb,
                                             float* __restrict__ out) {
    int tid = threadIdx.x;
    int lane = tid & 31, rsub = tid >> 5;
    int row = blockIdx.x * 8 + rsub;
    uint2 u = ((const uint2*)(h4 + (size_t)row * 128))[lane];
    float x0 = __uint_as_float(u.x << 16);
    float x1 = __uint_as_float(u.x & 0xffff0000u);
    float x2 = __uint_as_float(u.y << 16);
    float x3 = __uint_as_float(u.y & 0xffff0000u);
    float4 a = ((const float4*)(st4 + 256))[lane];
    float4 c = ((const float4*)(st4 + 384))[lane];
    x0 = a.x * x0 + c.x;
    x1 = a.y * x1 + c.y;
    x2 = a.z * x2 + c.z;
    x3 = a.w * x3 + c.w;
    const float4* W = (const float4*)(fcw + lane * 8);
    float4 w01 = W[0], w23 = W[1];
    float s0 = x0 * w01.x + x1 * w01.z + x2 * w23.x + x3 * w23.z;
    float s1 = x0 * w01.y + x1 * w01.w + x2 * w23.y + x3 * w23.w;
#pragma unroll
    for (int off = 16; off > 0; off >>= 1) {
        s0 += __shfl_down(s0, off, 32);
        s1 += __shfl_down(s1, off, 32);
    }
    if (lane == 0) {
        out[row * 2] = s0 + fcb[0];
        out[row * 2 + 1] = s1 + fcb[1];
    }
}

// ---------------------------------------------------------------------------

extern "C" void kernel_launch(void* const* d_in, const int* in_sizes, int n_in,
                              void* d_out, int out_size, void* d_ws, size_t ws_size,
                              hipStream_t stream) {
    const float* x = (const float*)d_in[0];
    const float* m1_w1 = (const float*)d_in[1];
    const float* m1_b1 = (const float*)d_in[2];
    const float* m1_w2 = (const float*)d_in[3];
    const float* m1_b2 = (const float*)d_in[4];
    const float* m1_g = (const float*)d_in[5];
    const float* m1_be = (const float*)d_in[6];
    const float* m2_w1 = (const float*)d_in[7];
    const float* m2_b1 = (const float*)d_in[8];
    const float* m2_w2 = (const float*)d_in[9];
    const float* m2_b2 = (const float*)d_in[10];
    const float* m2_g = (const float*)d_in[11];
    const float* m2_be = (const float*)d_in[12];
    const float* m3_w1 = (const float*)d_in[13];
    const float* m3_b1 = (const float*)d_in[14];
    const float* m3_w2 = (const float*)d_in[15];
    const float* m3_b2 = (const float*)d_in[16];
    const float* m3_g = (const float*)d_in[17];
    const float* m3_be = (const float*)d_in[18];
    const float* m4_w1 = (const float*)d_in[19];
    const float* m4_b1 = (const float*)d_in[20];
    const float* m4_w2 = (const float*)d_in[21];
    const float* m4_b2 = (const float*)d_in[22];
    const float* m4_g = (const float*)d_in[23];
    const float* m4_be = (const float*)d_in[24];
    const float* fc_w = (const float*)d_in[25];
    const float* fc_b = (const float*)d_in[26];
    float* out = (float*)d_out;

    // workspace layout (float offsets); aggraw aliases h1 (dead after k_pq).
    // total bytes = 3174400*4 + 258048*128*2 = 78,757,888.
    float* W = (float*)d_ws;
    float* stats = W;                   // 4 x 512
    float* cvec = W + 2048;             // 128
    float* h1 = W + 4096;               // 4096x128 (aliased by aggraw)
    float* aggraw = h1;
    float* P2 = W + 528384;
    float* Q2 = W + 1052672;
    float* h3 = W + 1576960;
    float* P4 = W + 2101248;
    float* Q4 = W + 2625536;
    _Float16* w2p2 = (_Float16*)(W + 3149824);  // 16384 fp16
    _Float16* w4p2 = (_Float16*)(W + 3158016);
    _Float16* wcp = (_Float16*)(W + 3166208);
    unsigned short* h4b = (unsigned short*)(W + 3174400);  // 258048x128 bf16

    if (ws_size < 78757888ull) return;  // safe-fail diagnostic (no OOB fault)

    k_zero<<<9, 256, 0, stream>>>(W);
    k_packw<<<8, 256, 0, stream>>>(m2_w2, w2p2);
    k_packw<<<8, 256, 0, stream>>>(m4_w2, w4p2);
    k_mlp1<<<64, 256, 0, stream>>>(x, m1_w1, m1_b1, m1_w2, m1_b2, h1, stats);
    k_finalize<<<1, 128, 0, stream>>>(stats, 1.f / 4096.f, m1_g, m1_be);
    k_pq<<<128, 256, 0, stream>>>(h1, stats, m2_w1, P2, Q2);
    k_mlp2agg<<<4096, 256, 0, stream>>>(P2, Q2, m2_b1, w2p2, m2_b2, aggraw, stats + 512);
    k_finalize<<<1, 128, 0, stream>>>(stats + 512, 1.f / 258048.f, m2_g, m2_be);
    k_wcprep<<<128, 128, 0, stream>>>(m4_w1, stats + 512, wcp, cvec);
    k_mlp3<<<64, 256, 0, stream>>>(aggraw, stats + 512, m3_w1, m3_b1, m3_w2, m3_b2, h3,
                                   stats + 1024);
    k_finalize<<<1, 128, 0, stream>>>(stats + 1024, 1.f / 4096.f, m3_g, m3_be);
    k_pq<<<128, 256, 0, stream>>>(h3, stats + 1024, m4_w1, P4, Q4);
    k_mlp4r<<<4032, 256, 0, stream>>>(P2, Q2, m2_b1, w2p2, m2_b2, P4, Q4, wcp, cvec,
                                      m4_b1, w4p2, m4_b2, h4b, stats + 1536);
    k_finalize<<<1, 128, 0, stream>>>(stats + 1536, 1.f / 258048.f, m4_g, m4_be);
    k_out<<<32256, 256, 0, stream>>>(h4b, stats + 1536, fc_w, fc_b, out);
}

// Round 7
// 373.431 us; speedup vs baseline: 1.2166x; 1.2166x over previous
//
#include <hip/hip_runtime.h>

#define BN_EPS 1e-5f

using h8 = __attribute__((ext_vector_type(8))) _Float16;
using f4v = __attribute__((ext_vector_type(4))) float;

// workspace float offsets
#define OFF_COEF 0        // 4 stages x 256 (a @ [0:128), shift @ [128:256))
#define OFF_CVEC 1024     // 128
#define OFF_H1 4096       // 4096x128 (aliased: aggraw; first 16384 = sums4)
#define OFF_P2 528384     // first 16384 floats = sums1 (dead until k_pq1)
#define OFF_Q2 1052672
#define OFF_H3 1576960
#define OFF_P4 2101248    // first 16384 = sums2 (dead until k_pq4)
#define OFF_Q4 2625536    // first 16384 = sums3 (dead until k_pq4)
#define OFF_W2P 3149824   // 16384 fp16 = 8192 floats each
#define OFF_W4P 3158016
#define OFF_WCP 3166208
#define OFF_H4B 3174400   // 258048x128 bf16
#define WS_BYTES 78757888ull

__device__ __forceinline__ float elu_f(float x) {
    return x > 0.f ? x : __expf(x) - 1.f;
}

__device__ __forceinline__ unsigned short bf16r(float x) {
    unsigned u = __float_as_uint(x);
    return (unsigned short)((u + 0x7fffu + ((u >> 16) & 1u)) >> 16);
}

// ---------------------------------------------------------------------------
// fp32 tile GEMM helpers (node-level kernels).
// ---------------------------------------------------------------------------

__device__ __forceinline__ void gemm_acc(float acc[4][8], float a0, float a1, float a2,
                                         float a3, const float4 wa, const float4 wb) {
    const float w[8] = {wa.x, wa.y, wa.z, wa.w, wb.x, wb.y, wb.z, wb.w};
    const float a[4] = {a0, a1, a2, a3};
#pragma unroll
    for (int j = 0; j < 4; ++j)
#pragma unroll
        for (int u = 0; u < 8; ++u)
            acc[j][u] = fmaf(a[j], w[u], acc[j][u]);
}

__device__ __forceinline__ void gemm_globalW(const float* As, int lda,
                                             const float* __restrict__ Wg, int K,
                                             float acc[4][8], int tx, int ty) {
    const float4* Wg4 = (const float4*)Wg;
#pragma unroll 4
    for (int k = 0; k < K; ++k) {
        float a0 = As[ty * lda + k];
        float a1 = As[(ty + 16) * lda + k];
        float a2 = As[(ty + 32) * lda + k];
        float a3 = As[(ty + 48) * lda + k];
        float4 wa = Wg4[k * 32 + tx];
        float4 wb = Wg4[k * 32 + 16 + tx];
        gemm_acc(acc, a0, a1, a2, a3, wa, wb);
    }
}

__device__ __forceinline__ void bias_elu(const float acc[4][8], const float* __restrict__ bias,
                                         float vals[4][8], int tx) {
    int ca = 4 * tx, cb = 64 + 4 * tx;
    float bv[8] = {bias[ca], bias[ca + 1], bias[ca + 2], bias[ca + 3],
                   bias[cb], bias[cb + 1], bias[cb + 2], bias[cb + 3]};
#pragma unroll
    for (int j = 0; j < 4; ++j)
#pragma unroll
        for (int u = 0; u < 8; ++u)
            vals[j][u] = elu_f(acc[j][u] + bv[u]);
}

__device__ __forceinline__ void store_tile(float* __restrict__ out, int row0,
                                           const float vals[4][8], int tx, int ty) {
#pragma unroll
    for (int j = 0; j < 4; ++j) {
        int r = row0 + ty + 16 * j;
        *(float4*)(out + r * 128 + 4 * tx) =
            make_float4(vals[j][0], vals[j][1], vals[j][2], vals[j][3]);
        *(float4*)(out + r * 128 + 64 + 4 * tx) =
            make_float4(vals[j][4], vals[j][5], vals[j][6], vals[j][7]);
    }
}

// st = this block's shadow copy base: [0:128) sum, [128:256) sumsq
__device__ __forceinline__ void stats_tail(const float vals[4][8], float* red,
                                           float* __restrict__ st, int tid, int tx, int ty) {
    float ls[8], lq[8];
#pragma unroll
    for (int u = 0; u < 8; ++u) {
        ls[u] = vals[0][u] + vals[1][u] + vals[2][u] + vals[3][u];
        lq[u] = vals[0][u] * vals[0][u] + vals[1][u] * vals[1][u] +
                vals[2][u] * vals[2][u] + vals[3][u] * vals[3][u];
    }
    __syncthreads();
    int ca = 4 * tx, cb = 64 + 4 * tx;
#pragma unroll
    for (int u = 0; u < 4; ++u) {
        red[ty * 128 + ca + u] = ls[u];
        red[2048 + ty * 128 + ca + u] = lq[u];
        red[ty * 128 + cb + u] = ls[u + 4];
        red[2048 + ty * 128 + cb + u] = lq[u + 4];
    }
    __syncthreads();
    if (tid < 128) {
        float s = 0.f, q = 0.f;
#pragma unroll
        for (int t = 0; t < 16; ++t) {
            s += red[t * 128 + tid];
            q += red[2048 + t * 128 + tid];
        }
        atomicAdd(st + tid, s);
        atomicAdd(st + 128 + tid, q);
    }
}

// ---------------------------------------------------------------------------
// MFMA helpers. A-frag LDS layout: Afr[((rt*4+kc)*64 + o*16 + m)*8 + j] =
// act[rt*16+m][kc*32+o*8+j] (fp16). Weights prepacked in GLOBAL:
// Wp[((ct*4+kc)*64 + L)*8 + j] = W[kc*32+(L>>4)*8+j][ct*16+(L&15)].
// Wave w computes rows 0..63 x cols [32w, 32w+32).
// ---------------------------------------------------------------------------

__device__ __forceinline__ void mfma_gemm_gw(const _Float16* Afr,
                                             const _Float16* __restrict__ wp,
                                             f4v acc[4][2], int lane, int w) {
#pragma unroll
    for (int kc = 0; kc < 4; ++kc) {
        h8 bf0 = *(const h8*)&wp[(((w * 2 + 0) * 4 + kc) * 64 + lane) * 8];
        h8 bf1 = *(const h8*)&wp[(((w * 2 + 1) * 4 + kc) * 64 + lane) * 8];
        h8 af[4];
#pragma unroll
        for (int rt = 0; rt < 4; ++rt)
            af[rt] = *(const h8*)&Afr[((rt * 4 + kc) * 64 + lane) * 8];
#pragma unroll
        for (int rt = 0; rt < 4; ++rt)
            acc[rt][0] = __builtin_amdgcn_mfma_f32_16x16x32_f16(af[rt], bf0, acc[rt][0], 0, 0, 0);
#pragma unroll
        for (int rt = 0; rt < 4; ++rt)
            acc[rt][1] = __builtin_amdgcn_mfma_f32_16x16x32_f16(af[rt], bf1, acc[rt][1], 0, 0, 0);
    }
}

__device__ __forceinline__ void vals_to_afrag(_Float16* Afr, const float vals[4][2][4],
                                              int lane, int w) {
    int cl = lane & 15, quad = lane >> 4;
#pragma unroll
    for (int ctl = 0; ctl < 2; ++ctl) {
        int col = (w * 2 + ctl) * 16 + cl;
        int kc = col >> 5, o = (col >> 3) & 3, j = col & 7;
#pragma unroll
        for (int rt = 0; rt < 4; ++rt)
#pragma unroll
            for (int i = 0; i < 4; ++i) {
                int m = quad * 4 + i;
                Afr[((rt * 4 + kc) * 64 + o * 16 + m) * 8 + j] = (_Float16)vals[rt][ctl][i];
            }
    }
}

// ---------------------------------------------------------------------------
// Kernels
// ---------------------------------------------------------------------------

// zero the three pre-stage shadow-sum arenas + cvec (all alias dead regions)
__global__ void k_zero3(float* W) {
    int i = blockIdx.x * 256 + threadIdx.x;
    if (i < 16384) W[OFF_P2 + i] = 0.f;
    else if (i < 32768) W[OFF_P4 + i - 16384] = 0.f;
    else if (i < 49152) W[OFF_Q4 + i - 32768] = 0.f;
    else if (i < 49280) W[OFF_CVEC + i - 49152] = 0.f;
}

// reduce 64 shadow copies -> BN affine coefficients; optionally zero zbuf[0:16384)
__global__ void k_finalize(const float* __restrict__ sums, float* __restrict__ coef,
                           float invM, const float* __restrict__ g,
                           const float* __restrict__ beta, float* __restrict__ zbuf) {
    int c = threadIdx.x;  // 128
    float s = 0.f, q = 0.f;
#pragma unroll 8
    for (int t = 0; t < 64; ++t) {
        s += sums[t * 256 + c];
        q += sums[t * 256 + 128 + c];
    }
    float mean = s * invM;
    float var = q * invM - mean * mean;
    float a = g[c] * rsqrtf(var + BN_EPS);
    coef[c] = a;
    coef[128 + c] = beta[c] - mean * a;
    if (zbuf)
        for (int i = c; i < 16384; i += 128) zbuf[i] = 0.f;
}

// pack fp32 W[128][128] into MFMA-B fp16 frag layout
__global__ void k_packw(const float* __restrict__ w, _Float16* __restrict__ wp) {
    int flat = blockIdx.x * 256 + threadIdx.x;  // 0..2047
    int g = flat >> 6, L = flat & 63;
    int ct = g >> 2, kc = g & 3;
    int n = ct * 16 + (L & 15), k0 = kc * 32 + (L >> 4) * 8;
    h8 v;
#pragma unroll
    for (int j = 0; j < 8; ++j) v[j] = (_Float16)w[(k0 + j) * 128 + n];
    *(h8*)&wp[flat * 8] = v;
}

// mlp1: rows = B*N = 4096, K1 = 40 (transposed gather of inputs), K2 = 128. fp32.
__global__ __launch_bounds__(256) void k_mlp1(const float* __restrict__ x,
                                              const float* __restrict__ w1,
                                              const float* __restrict__ b1,
                                              const float* __restrict__ w2,
                                              const float* __restrict__ b2,
                                              float* __restrict__ h1, float* __restrict__ st) {
    __shared__ float Xs[64 * 44];
    __shared__ float As[64 * 132];
    int tid = threadIdx.x, tx = tid & 15, ty = tid >> 4;
    int r0 = blockIdx.x * 64;
    for (int idx = tid; idx < 64 * 40; idx += 256) {
        int r = idx / 40, k = idx - r * 40;
        int rr = r0 + r, b = rr >> 6, n = rr & 63, t = k >> 2, d = k & 3;
        Xs[r * 44 + k] = x[((b * 10 + t) * 64 + n) * 4 + d];
    }
    __syncthreads();
    float acc[4][8] = {};
    gemm_globalW(Xs, 44, w1, 40, acc, tx, ty);
    float vals[4][8];
    bias_elu(acc, b1, vals, tx);
    int ca = 4 * tx, cb = 64 + 4 * tx;
#pragma unroll
    for (int j = 0; j < 4; ++j) {
        int r = ty + 16 * j;
#pragma unroll
        for (int u = 0; u < 4; ++u) {
            As[r * 132 + ca + u] = vals[j][u];
            As[r * 132 + cb + u] = vals[j][u + 4];
        }
    }
    __syncthreads();
    float acc2[4][8] = {};
    gemm_globalW(As, 132, w2, 128, acc2, tx, ty);
    float vals2[4][8];
    bias_elu(acc2, b2, vals2, tx);
    store_tile(h1, r0, vals2, tx, ty);
    stats_tail(vals2, As, st + (blockIdx.x & 63) * 256, tid, tx, ty);
}

// P/Q precompute: P = BN(h) @ W[0:128], Q = BN(h) @ W[128:256]. fp32, 128 blocks.
__global__ __launch_bounds__(256) void k_pq(const float* __restrict__ h,
                                            const float* __restrict__ coef,
                                            const float* __restrict__ w,
                                            float* __restrict__ P, float* __restrict__ Q) {
    __shared__ float As[64 * 132];
    int tid = threadIdx.x, tx = tid & 15, ty = tid >> 4;
    int half = blockIdx.x >> 6;
    int r0 = (blockIdx.x & 63) * 64;
    const float* Wg = w + half * 128 * 128;
    float* out = half ? Q : P;
    const float4* h4 = (const float4*)h;
    const float4* av = (const float4*)coef;
    const float4* cv = (const float4*)(coef + 128);
#pragma unroll
    for (int i = 0; i < 8; ++i) {
        int f4 = tid + i * 256;
        int r = f4 >> 5, c4 = f4 & 31;
        float4 hv = h4[(r0 + r) * 32 + c4];
        float4 a = av[c4], c = cv[c4];
        float4 v;
        v.x = a.x * hv.x + c.x;
        v.y = a.y * hv.y + c.y;
        v.z = a.z * hv.z + c.z;
        v.w = a.w * hv.w + c.w;
        *(float4*)(As + r * 132 + c4 * 4) = v;
    }
    __syncthreads();
    float acc[4][8] = {};
    gemm_globalW(As, 132, Wg, 128, acc, tx, ty);
#pragma unroll
    for (int j = 0; j < 4; ++j) {
        int r = r0 + ty + 16 * j;
        *(float4*)(out + r * 128 + 4 * tx) = make_float4(acc[j][0], acc[j][1], acc[j][2], acc[j][3]);
        *(float4*)(out + r * 128 + 64 + 4 * tx) = make_float4(acc[j][4], acc[j][5], acc[j][6], acc[j][7]);
    }
}

// Recv-major fused mlp2 + edge2node (MFMA). One block per (b, recv n).
__global__ __launch_bounds__(256, 8) void k_mlp2agg(const float* __restrict__ P2,
                                                    const float* __restrict__ Q2,
                                                    const float* __restrict__ b1,
                                                    const _Float16* __restrict__ w2p,
                                                    const float* __restrict__ b2,
                                                    float* __restrict__ aggraw,
                                                    float* __restrict__ st) {
    __shared__ _Float16 Afr[8192];  // 16 KB
    int tid = threadIdx.x;
    int lane = tid & 63, w = tid >> 6;
    int b = blockIdx.x >> 6, n = blockIdx.x & 63;
    float* stc = st + (blockIdx.x & 63) * 256;
    {
        int r = lane, kc = w;
        int s = (r < 63) ? (r + (r >= n ? 1 : 0)) : n;  // row 63: dummy
        const float4* Pr = (const float4*)(P2 + (b * 64 + s) * 128);
        const float4* Qr = (const float4*)(Q2 + (b * 64 + n) * 128);
        const float4* B1 = (const float4*)b1;
        int rt = r >> 4, m = r & 15;
#pragma unroll
        for (int o = 0; o < 4; ++o) {
            int c4 = kc * 8 + o * 2;
            float4 p0 = Pr[c4], q0 = Qr[c4], bb0 = B1[c4];
            float4 p1 = Pr[c4 + 1], q1 = Qr[c4 + 1], bb1 = B1[c4 + 1];
            h8 v;
            v[0] = (_Float16)elu_f(p0.x + q0.x + bb0.x);
            v[1] = (_Float16)elu_f(p0.y + q0.y + bb0.y);
            v[2] = (_Float16)elu_f(p0.z + q0.z + bb0.z);
            v[3] = (_Float16)elu_f(p0.w + q0.w + bb0.w);
            v[4] = (_Float16)elu_f(p1.x + q1.x + bb1.x);
            v[5] = (_Float16)elu_f(p1.y + q1.y + bb1.y);
            v[6] = (_Float16)elu_f(p1.z + q1.z + bb1.z);
            v[7] = (_Float16)elu_f(p1.w + q1.w + bb1.w);
            *(h8*)&Afr[((rt * 4 + kc) * 64 + o * 16 + m) * 8] = v;
        }
    }
    __syncthreads();
    f4v acc[4][2];
#pragma unroll
    for (int rt = 0; rt < 4; ++rt)
#pragma unroll
        for (int c = 0; c < 2; ++c) acc[rt][c] = (f4v){0.f, 0.f, 0.f, 0.f};
    mfma_gemm_gw(Afr, w2p, acc, lane, w);
    int cl = lane & 15, quad = lane >> 4;
#pragma unroll
    for (int ctl = 0; ctl < 2; ++ctl) {
        int col = (w * 2 + ctl) * 16 + cl;
        float bias = b2[col];
        float s1 = 0.f, s2 = 0.f;
#pragma unroll
        for (int rt = 0; rt < 4; ++rt)
#pragma unroll
            for (int i = 0; i < 4; ++i) {
                int row = rt * 16 + quad * 4 + i;
                float v = elu_f(acc[rt][ctl][i] + bias);
                if (row == 63) v = 0.f;
                s1 += v;
                s2 += v * v;
            }
        s1 += __shfl_xor(s1, 16);
        s2 += __shfl_xor(s2, 16);
        s1 += __shfl_xor(s1, 32);
        s2 += __shfl_xor(s2, 32);
        if (quad == 0) {
            aggraw[(b * 64 + n) * 128 + col] = s1;
            atomicAdd(stc + col, s1);
            atomicAdd(stc + 128 + col, s2);
        }
    }
}

// prep for mlp4 skip path: wcp (fp16, MFMA-B layout) = a2[k]*W4_1[256+k][c];
// cvec[c] += shift2[k]*W4_1[256+k][c]
__global__ void k_wcprep(const float* __restrict__ w41, const float* __restrict__ coef2,
                         _Float16* __restrict__ wcp, float* __restrict__ cvec) {
    int k = blockIdx.x, c = threadIdx.x;  // 128 x 128
    float wv = w41[(256 + k) * 128 + c];
    int g = (c >> 4) * 4 + (k >> 5);
    int L = ((k >> 3) & 3) * 16 + (c & 15);
    int j = k & 7;
    wcp[(g * 64 + L) * 8 + j] = (_Float16)(coef2[k] * wv);
    atomicAdd(&cvec[c], coef2[128 + k] * wv);
}

// mlp3: rows = 4096, input = a2*(aggraw/63)+shift2, K=128 both layers. fp32.
__global__ __launch_bounds__(256) void k_mlp3(const float* __restrict__ raw,
                                              const float* __restrict__ coef2,
                                              const float* __restrict__ w1,
                                              const float* __restrict__ b1,
                                              const float* __restrict__ w2,
                                              const float* __restrict__ b2,
                                              float* __restrict__ h3, float* __restrict__ st) {
    __shared__ float As[64 * 132];
    int tid = threadIdx.x, tx = tid & 15, ty = tid >> 4;
    int r0 = blockIdx.x * 64;
    const float4* in4 = (const float4*)raw;
    const float4* av = (const float4*)coef2;
    const float4* cv = (const float4*)(coef2 + 128);
    const float inv63 = 1.f / 63.f;
#pragma unroll
    for (int i = 0; i < 8; ++i) {
        int f4 = tid + i * 256;
        int r = f4 >> 5, c4 = f4 & 31;
        float4 hv = in4[(r0 + r) * 32 + c4];
        float4 a = av[c4], c = cv[c4];
        float4 v;
        v.x = a.x * hv.x * inv63 + c.x;
        v.y = a.y * hv.y * inv63 + c.y;
        v.z = a.z * hv.z * inv63 + c.z;
        v.w = a.w * hv.w * inv63 + c.w;
        *(float4*)(As + r * 132 + c4 * 4) = v;
    }
    __syncthreads();
    float acc[4][8] = {};
    gemm_globalW(As, 132, w1, 128, acc, tx, ty);
    float vals[4][8];
    bias_elu(acc, b1, vals, tx);
    __syncthreads();
    int ca = 4 * tx, cb = 64 + 4 * tx;
#pragma unroll
    for (int j = 0; j < 4; ++j) {
        int r = ty + 16 * j;
#pragma unroll
        for (int u = 0; u < 4; ++u) {
            As[r * 132 + ca + u] = vals[j][u];
            As[r * 132 + cb + u] = vals[j][u + 4];
        }
    }
    __syncthreads();
    float acc2[4][8] = {};
    gemm_globalW(As, 132, w2, 128, acc2, tx, ty);
    float vals2[4][8];
    bias_elu(acc2, b2, vals2, tx);
    store_tile(h3, r0, vals2, tx, ty);
    stats_tail(vals2, As, st + (blockIdx.x & 63) * 256, tid, tx, ty);
}

// mlp4 edge kernel (MFMA, send-major tiles). GEMM1 recomputes h2 from P2/Q2,
// GEMM2 = skip path h2 @ Wc', GEMM3 = mlp4 layer 2. P4/Q4 gather terms are
// pre-staged into LDS (T4s, fp16, stride 136 halfs = 272 B, h8 stores aligned).
__global__ __launch_bounds__(256, 4) void k_mlp4r(const float* __restrict__ P2,
                                                  const float* __restrict__ Q2,
                                                  const float* __restrict__ m2b1,
                                                  const _Float16* __restrict__ w2p2,
                                                  const float* __restrict__ m2b2,
                                                  const float* __restrict__ P4,
                                                  const float* __restrict__ Q4,
                                                  const _Float16* __restrict__ wcp,
                                                  const float* __restrict__ cvec,
                                                  const float* __restrict__ b1,
                                                  const _Float16* __restrict__ w4p2,
                                                  const float* __restrict__ b2,
                                                  unsigned short* __restrict__ h4,
                                                  float* __restrict__ st) {
    __shared__ _Float16 Afr[8192];       // 16 KB (reused as bf16 bounce tile)
    __shared__ _Float16 T4s[64 * 136];   // 17 KB: P4[s]+Q4[rv]+b1+cvec
    int tid = threadIdx.x;
    int lane = tid & 63, w = tid >> 6;
    unsigned blk = blockIdx.x;
    unsigned b = blk / 63;
    unsigned e0 = (blk - b * 63) * 64;
    int row0 = blk * 64;
    int cl = lane & 15, quad = lane >> 4;
    float* stc = st + (blk & 63) * 256;
    {  // staging: r = lane, kc = w; A_skip -> Afr, P4/Q4 gather -> T4s
        int r = lane, kc = w;
        unsigned e = e0 + r;
        unsigned s = e / 63;
        unsigned jj = e - s * 63;
        unsigned rv = jj + (jj >= s ? 1u : 0u);
        const float4* P2r = (const float4*)(P2 + (b * 64 + s) * 128);
        const float4* Q2r = (const float4*)(Q2 + (b * 64 + rv) * 128);
        const float4* P4r = (const float4*)(P4 + (b * 64 + s) * 128);
        const float4* Q4r = (const float4*)(Q4 + (b * 64 + rv) * 128);
        const float4* B1a = (const float4*)m2b1;
        const float4* B1b = (const float4*)b1;
        const float4* CV = (const float4*)cvec;
        int rt = r >> 4, m = r & 15;
#pragma unroll
        for (int o = 0; o < 4; ++o) {
            int c4 = kc * 8 + o * 2;
            float4 p0 = P2r[c4], q0 = Q2r[c4], bb0 = B1a[c4];
            float4 p1 = P2r[c4 + 1], q1 = Q2r[c4 + 1], bb1 = B1a[c4 + 1];
            h8 v;
            v[0] = (_Float16)elu_f(p0.x + q0.x + bb0.x);
            v[1] = (_Float16)elu_f(p0.y + q0.y + bb0.y);
            v[2] = (_Float16)elu_f(p0.z + q0.z + bb0.z);
            v[3] = (_Float16)elu_f(p0.w + q0.w + bb0.w);
            v[4] = (_Float16)elu_f(p1.x + q1.x + bb1.x);
            v[5] = (_Float16)elu_f(p1.y + q1.y + bb1.y);
            v[6] = (_Float16)elu_f(p1.z + q1.z + bb1.z);
            v[7] = (_Float16)elu_f(p1.w + q1.w + bb1.w);
            *(h8*)&Afr[((rt * 4 + kc) * 64 + o * 16 + m) * 8] = v;
            float4 a0 = P4r[c4], d0 = Q4r[c4], e0v = B1b[c4], f0 = CV[c4];
            float4 a1 = P4r[c4 + 1], d1 = Q4r[c4 + 1], e1v = B1b[c4 + 1], f1 = CV[c4 + 1];
            h8 t;
            t[0] = (_Float16)(a0.x + d0.x + e0v.x + f0.x);
            t[1] = (_Float16)(a0.y + d0.y + e0v.y + f0.y);
            t[2] = (_Float16)(a0.z + d0.z + e0v.z + f0.z);
            t[3] = (_Float16)(a0.w + d0.w + e0v.w + f0.w);
            t[4] = (_Float16)(a1.x + d1.x + e1v.x + f1.x);
            t[5] = (_Float16)(a1.y + d1.y + e1v.y + f1.y);
            t[6] = (_Float16)(a1.z + d1.z + e1v.z + f1.z);
            t[7] = (_Float16)(a1.w + d1.w + e1v.w + f1.w);
            *(h8*)&T4s[r * 136 + kc * 32 + o * 8] = t;
        }
    }
    __syncthreads();
    f4v acc[4][2];
#pragma unroll
    for (int rt = 0; rt < 4; ++rt)
#pragma unroll
        for (int c = 0; c < 2; ++c) acc[rt][c] = (f4v){0.f, 0.f, 0.f, 0.f};
    mfma_gemm_gw(Afr, w2p2, acc, lane, w);
    // epilogue 1: h2 = elu(acc + m2b2[col])
    float vals[4][2][4];
#pragma unroll
    for (int ctl = 0; ctl < 2; ++ctl) {
        float bias = m2b2[(w * 2 + ctl) * 16 + cl];
#pragma unroll
        for (int rt = 0; rt < 4; ++rt)
#pragma unroll
            for (int i = 0; i < 4; ++i)
                vals[rt][ctl][i] = elu_f(acc[rt][ctl][i] + bias);
    }
    __syncthreads();
    vals_to_afrag(Afr, vals, lane, w);
    __syncthreads();
#pragma unroll
    for (int rt = 0; rt < 4; ++rt)
#pragma unroll
        for (int c = 0; c < 2; ++c) acc[rt][c] = (f4v){0.f, 0.f, 0.f, 0.f};
    mfma_gemm_gw(Afr, wcp, acc, lane, w);
    // epilogue 2: pre1 = acc + T4s[row][col] -> elu
#pragma unroll
    for (int ctl = 0; ctl < 2; ++ctl) {
        int col = (w * 2 + ctl) * 16 + cl;
#pragma unroll
        for (int rt = 0; rt < 4; ++rt)
#pragma unroll
            for (int i = 0; i < 4; ++i) {
                int row = rt * 16 + quad * 4 + i;
                float t = (float)T4s[row * 136 + col];
                vals[rt][ctl][i] = elu_f(acc[rt][ctl][i] + t);
            }
    }
    __syncthreads();
    vals_to_afrag(Afr, vals, lane, w);
    __syncthreads();
#pragma unroll
    for (int rt = 0; rt < 4; ++rt)
#pragma unroll
        for (int c = 0; c < 2; ++c) acc[rt][c] = (f4v){0.f, 0.f, 0.f, 0.f};
    mfma_gemm_gw(Afr, w4p2, acc, lane, w);
    // epilogue 3: h4 = elu(acc + b2[col]); stats; bf16 store via LDS bounce
    unsigned short* Tile = (unsigned short*)Afr;
#pragma unroll
    for (int ctl = 0; ctl < 2; ++ctl) {
        int col = (w * 2 + ctl) * 16 + cl;
        float bias = b2[col];
        float s1 = 0.f, s2 = 0.f;
#pragma unroll
        for (int rt = 0; rt < 4; ++rt)
#pragma unroll
            for (int i = 0; i < 4; ++i) {
                float v = elu_f(acc[rt][ctl][i] + bias);
                vals[rt][ctl][i] = v;
                s1 += v;
                s2 += v * v;
            }
        s1 += __shfl_xor(s1, 16);
        s2 += __shfl_xor(s2, 16);
        s1 += __shfl_xor(s1, 32);
        s2 += __shfl_xor(s2, 32);
        if (quad == 0) {
            atomicAdd(stc + col, s1);
            atomicAdd(stc + 128 + col, s2);
        }
    }
    __syncthreads();
#pragma unroll
    for (int ctl = 0; ctl < 2; ++ctl) {
        int col = (w * 2 + ctl) * 16 + cl;
#pragma unroll
        for (int rt = 0; rt < 4; ++rt)
#pragma unroll
            for (int i = 0; i < 4; ++i)
                Tile[(rt * 16 + quad * 4 + i) * 128 + col] = bf16r(vals[rt][ctl][i]);
    }
    __syncthreads();
    {
        int r = tid >> 2, cq = tid & 3;
#pragma unroll
        for (int i = 0; i < 4; ++i) {
            int off = r * 128 + cq * 32 + i * 8;
            *(uint4*)(h4 + (size_t)row0 * 128 + off) = *(uint4*)&Tile[off];
        }
    }
}

// final: out[row,k] = sum_c (a4[c]*h4[row,c]+shift4[c]) * fcw[c,k] + fcb[k]
__global__ __launch_bounds__(256) void k_out(const unsigned short* __restrict__ h4,
                                             const float* __restrict__ coef4,
                                             const float* __restrict__ fcw,
                                             const float* __restrict__ fcb,
                                             float* __restrict__ out) {
    int tid = threadIdx.x;
    int lane = tid & 31, rsub = tid >> 5;
    int row = blockIdx.x * 8 + rsub;
    uint2 u = ((const uint2*)(h4 + (size_t)row * 128))[lane];
    float x0 = __uint_as_float(u.x << 16);
    float x1 = __uint_as_float(u.x & 0xffff0000u);
    float x2 = __uint_as_float(u.y << 16);
    float x3 = __uint_as_float(u.y & 0xffff0000u);
    float4 a = ((const float4*)coef4)[lane];
    float4 c = ((const float4*)(coef4 + 128))[lane];
    x0 = a.x * x0 + c.x;
    x1 = a.y * x1 + c.y;
    x2 = a.z * x2 + c.z;
    x3 = a.w * x3 + c.w;
    const float4* W = (const float4*)(fcw + lane * 8);
    float4 w01 = W[0], w23 = W[1];
    float s0 = x0 * w01.x + x1 * w01.z + x2 * w23.x + x3 * w23.z;
    float s1 = x0 * w01.y + x1 * w01.w + x2 * w23.y + x3 * w23.w;
#pragma unroll
    for (int off = 16; off > 0; off >>= 1) {
        s0 += __shfl_down(s0, off, 32);
        s1 += __shfl_down(s1, off, 32);
    }
    if (lane == 0) {
        out[row * 2] = s0 + fcb[0];
        out[row * 2 + 1] = s1 + fcb[1];
    }
}

// ---------------------------------------------------------------------------

extern "C" void kernel_launch(void* const* d_in, const int* in_sizes, int n_in,
                              void* d_out, int out_size, void* d_ws, size_t ws_size,
                              hipStream_t stream) {
    const float* x = (const float*)d_in[0];
    const float* m1_w1 = (const float*)d_in[1];
    const float* m1_b1 = (const float*)d_in[2];
    const float* m1_w2 = (const float*)d_in[3];
    const float* m1_b2 = (const float*)d_in[4];
    const float* m1_g = (const float*)d_in[5];
    const float* m1_be = (const float*)d_in[6];
    const float* m2_w1 = (const float*)d_in[7];
    const float* m2_b1 = (const float*)d_in[8];
    const float* m2_w2 = (const float*)d_in[9];
    const float* m2_b2 = (const float*)d_in[10];
    const float* m2_g = (const float*)d_in[11];
    const float* m2_be = (const float*)d_in[12];
    const float* m3_w1 = (const float*)d_in[13];
    const float* m3_b1 = (const float*)d_in[14];
    const float* m3_w2 = (const float*)d_in[15];
    const float* m3_b2 = (const float*)d_in[16];
    const float* m3_g = (const float*)d_in[17];
    const float* m3_be = (const float*)d_in[18];
    const float* m4_w1 = (const float*)d_in[19];
    const float* m4_b1 = (const float*)d_in[20];
    const float* m4_w2 = (const float*)d_in[21];
    const float* m4_b2 = (const float*)d_in[22];
    const float* m4_g = (const float*)d_in[23];
    const float* m4_be = (const float*)d_in[24];
    const float* fc_w = (const float*)d_in[25];
    const float* fc_b = (const float*)d_in[26];
    float* out = (float*)d_out;

    float* W = (float*)d_ws;
    float* coef1 = W + OFF_COEF;
    float* coef2 = W + OFF_COEF + 256;
    float* coef3 = W + OFF_COEF + 512;
    float* coef4 = W + OFF_COEF + 768;
    float* cvec = W + OFF_CVEC;
    float* h1 = W + OFF_H1;        // aliased: aggraw; sums4 = h1[0:16384)
    float* aggraw = h1;
    float* sums4 = h1;
    float* P2 = W + OFF_P2;        // sums1 = P2[0:16384) (dead until k_pq1)
    float* sums1 = P2;
    float* Q2 = W + OFF_Q2;
    float* h3 = W + OFF_H3;
    float* P4 = W + OFF_P4;        // sums2 = P4[0:16384) (dead until k_pq4)
    float* sums2 = P4;
    float* Q4 = W + OFF_Q4;        // sums3 = Q4[0:16384) (dead until k_pq4)
    float* sums3 = Q4;
    _Float16* w2p2 = (_Float16*)(W + OFF_W2P);
    _Float16* w4p2 = (_Float16*)(W + OFF_W4P);
    _Float16* wcp = (_Float16*)(W + OFF_WCP);
    unsigned short* h4b = (unsigned short*)(W + OFF_H4B);

    if (ws_size < WS_BYTES) return;  // safe-fail diagnostic (no OOB fault)

    k_zero3<<<193, 256, 0, stream>>>(W);
    k_packw<<<8, 256, 0, stream>>>(m2_w2, w2p2);
    k_packw<<<8, 256, 0, stream>>>(m4_w2, w4p2);
    k_mlp1<<<64, 256, 0, stream>>>(x, m1_w1, m1_b1, m1_w2, m1_b2, h1, sums1);
    k_finalize<<<1, 128, 0, stream>>>(sums1, coef1, 1.f / 4096.f, m1_g, m1_be, nullptr);
    k_pq<<<128, 256, 0, stream>>>(h1, coef1, m2_w1, P2, Q2);
    k_mlp2agg<<<4096, 256, 0, stream>>>(P2, Q2, m2_b1, w2p2, m2_b2, aggraw, sums2);
    k_finalize<<<1, 128, 0, stream>>>(sums2, coef2, 1.f / 258048.f, m2_g, m2_be, nullptr);
    k_wcprep<<<128, 128, 0, stream>>>(m4_w1, coef2, wcp, cvec);
    k_mlp3<<<64, 256, 0, stream>>>(aggraw, coef2, m3_w1, m3_b1, m3_w2, m3_b2, h3, sums3);
    k_finalize<<<1, 128, 0, stream>>>(sums3, coef3, 1.f / 4096.f, m3_g, m3_be, sums4);
    k_pq<<<128, 256, 0, stream>>>(h3, coef3, m4_w1, P4, Q4);
    k_mlp4r<<<4032, 256, 0, stream>>>(P2, Q2, m2_b1, w2p2, m2_b2, P4, Q4, wcp, cvec,
                                      m4_b1, w4p2, m4_b2, h4b, sums4);
    k_finalize<<<1, 128, 0, stream>>>(sums4, coef4, 1.f / 258048.f, m4_g, m4_be, nullptr);
    k_out<<<32256, 256, 0, stream>>>(h4b, coef4, fc_w, fc_b, out);
}

// Round 10
// 373.048 us; speedup vs baseline: 1.2179x; 1.0010x over previous
//
#include <hip/hip_runtime.h>

#define BN_EPS 1e-5f

using h8 = __attribute__((ext_vector_type(8))) _Float16;
using f4v = __attribute__((ext_vector_type(4))) float;

// workspace float offsets (round-7 proven layout)
#define OFF_COEF 0        // 4 stages x 256 (a @ [0:128), shift @ [128:256))
#define OFF_CVEC 1024     // 128
#define OFF_H1 4096       // 4096x128 (aliased: aggraw; first 16384 = sums4)
#define OFF_P2 528384     // first 16384 floats = sums1 (dead until k_pq1)
#define OFF_Q2 1052672
#define OFF_H3 1576960
#define OFF_P4 2101248    // first 16384 = sums2 (dead until k_pq4)
#define OFF_Q4 2625536    // first 16384 = sums3 (dead until k_pq4)
#define OFF_W2P 3149824   // 16384 fp16 = 8192 floats each
#define OFF_W4P 3158016
#define OFF_WCP 3166208
#define OFF_H4B 3174400   // 258048x128 bf16
#define WS_BYTES 78757888ull

__device__ __forceinline__ float elu_f(float x) {
    return x > 0.f ? x : __expf(x) - 1.f;
}

__device__ __forceinline__ unsigned short bf16r(float x) {
    unsigned u = __float_as_uint(x);
    return (unsigned short)((u + 0x7fffu + ((u >> 16) & 1u)) >> 16);
}

// ---------------------------------------------------------------------------
// fp32 tile GEMM helpers (node-level kernels) - round-7 proven.
// ---------------------------------------------------------------------------

__device__ __forceinline__ void gemm_acc(float acc[4][8], float a0, float a1, float a2,
                                         float a3, const float4 wa, const float4 wb) {
    const float w[8] = {wa.x, wa.y, wa.z, wa.w, wb.x, wb.y, wb.z, wb.w};
    const float a[4] = {a0, a1, a2, a3};
#pragma unroll
    for (int j = 0; j < 4; ++j)
#pragma unroll
        for (int u = 0; u < 8; ++u)
            acc[j][u] = fmaf(a[j], w[u], acc[j][u]);
}

__device__ __forceinline__ void gemm_globalW(const float* As, int lda,
                                             const float* __restrict__ Wg, int K,
                                             float acc[4][8], int tx, int ty) {
    const float4* Wg4 = (const float4*)Wg;
#pragma unroll 4
    for (int k = 0; k < K; ++k) {
        float a0 = As[ty * lda + k];
        float a1 = As[(ty + 16) * lda + k];
        float a2 = As[(ty + 32) * lda + k];
        float a3 = As[(ty + 48) * lda + k];
        float4 wa = Wg4[k * 32 + tx];
        float4 wb = Wg4[k * 32 + 16 + tx];
        gemm_acc(acc, a0, a1, a2, a3, wa, wb);
    }
}

__device__ __forceinline__ void bias_elu(const float acc[4][8], const float* __restrict__ bias,
                                         float vals[4][8], int tx) {
    int ca = 4 * tx, cb = 64 + 4 * tx;
    float bv[8] = {bias[ca], bias[ca + 1], bias[ca + 2], bias[ca + 3],
                   bias[cb], bias[cb + 1], bias[cb + 2], bias[cb + 3]};
#pragma unroll
    for (int j = 0; j < 4; ++j)
#pragma unroll
        for (int u = 0; u < 8; ++u)
            vals[j][u] = elu_f(acc[j][u] + bv[u]);
}

__device__ __forceinline__ void store_tile(float* __restrict__ out, int row0,
                                           const float vals[4][8], int tx, int ty) {
#pragma unroll
    for (int j = 0; j < 4; ++j) {
        int r = row0 + ty + 16 * j;
        *(float4*)(out + r * 128 + 4 * tx) =
            make_float4(vals[j][0], vals[j][1], vals[j][2], vals[j][3]);
        *(float4*)(out + r * 128 + 64 + 4 * tx) =
            make_float4(vals[j][4], vals[j][5], vals[j][6], vals[j][7]);
    }
}

__device__ __forceinline__ void stats_tail(const float vals[4][8], float* red,
                                           float* __restrict__ st, int tid, int tx, int ty) {
    float ls[8], lq[8];
#pragma unroll
    for (int u = 0; u < 8; ++u) {
        ls[u] = vals[0][u] + vals[1][u] + vals[2][u] + vals[3][u];
        lq[u] = vals[0][u] * vals[0][u] + vals[1][u] * vals[1][u] +
                vals[2][u] * vals[2][u] + vals[3][u] * vals[3][u];
    }
    __syncthreads();
    int ca = 4 * tx, cb = 64 + 4 * tx;
#pragma unroll
    for (int u = 0; u < 4; ++u) {
        red[ty * 128 + ca + u] = ls[u];
        red[2048 + ty * 128 + ca + u] = lq[u];
        red[ty * 128 + cb + u] = ls[u + 4];
        red[2048 + ty * 128 + cb + u] = lq[u + 4];
    }
    __syncthreads();
    if (tid < 128) {
        float s = 0.f, q = 0.f;
#pragma unroll
        for (int t = 0; t < 16; ++t) {
            s += red[t * 128 + tid];
            q += red[2048 + t * 128 + tid];
        }
        atomicAdd(st + tid, s);
        atomicAdd(st + 128 + tid, q);
    }
}

// ---------------------------------------------------------------------------
// MFMA helpers (round-7 proven). A-frag LDS layout:
// Afr[((rt*4+kc)*64 + o*16 + m)*8 + j] = act[rt*16+m][kc*32+o*8+j] (fp16).
// Weights prepacked in GLOBAL: Wp[((ct*4+kc)*64+L)*8+j] =
// W[kc*32+(L>>4)*8+j][ct*16+(L&15)]. Wave w computes rows 0..63 x cols
// [32w, 32w+32). gemm2_gw: one weight-frag load feeds BOTH tiles' MFMAs.
// ---------------------------------------------------------------------------

__device__ __forceinline__ void gemm2_gw(const _Float16* A0, const _Float16* A1,
                                         const _Float16* __restrict__ wp,
                                         f4v acc0[4][2], f4v acc1[4][2], int lane, int w) {
#pragma unroll
    for (int kc = 0; kc < 4; ++kc) {
        h8 bf0 = *(const h8*)&wp[(((w * 2 + 0) * 4 + kc) * 64 + lane) * 8];
        h8 bf1 = *(const h8*)&wp[(((w * 2 + 1) * 4 + kc) * 64 + lane) * 8];
        h8 af0[4], af1[4];
#pragma unroll
        for (int rt = 0; rt < 4; ++rt) {
            af0[rt] = *(const h8*)&A0[((rt * 4 + kc) * 64 + lane) * 8];
            af1[rt] = *(const h8*)&A1[((rt * 4 + kc) * 64 + lane) * 8];
        }
#pragma unroll
        for (int rt = 0; rt < 4; ++rt) {
            acc0[rt][0] = __builtin_amdgcn_mfma_f32_16x16x32_f16(af0[rt], bf0, acc0[rt][0], 0, 0, 0);
            acc1[rt][0] = __builtin_amdgcn_mfma_f32_16x16x32_f16(af1[rt], bf0, acc1[rt][0], 0, 0, 0);
        }
#pragma unroll
        for (int rt = 0; rt < 4; ++rt) {
            acc0[rt][1] = __builtin_amdgcn_mfma_f32_16x16x32_f16(af0[rt], bf1, acc0[rt][1], 0, 0, 0);
            acc1[rt][1] = __builtin_amdgcn_mfma_f32_16x16x32_f16(af1[rt], bf1, acc1[rt][1], 0, 0, 0);
        }
    }
}

__device__ __forceinline__ void mfma_gemm_gw(const _Float16* Afr,
                                             const _Float16* __restrict__ wp,
                                             f4v acc[4][2], int lane, int w) {
#pragma unroll
    for (int kc = 0; kc < 4; ++kc) {
        h8 bf0 = *(const h8*)&wp[(((w * 2 + 0) * 4 + kc) * 64 + lane) * 8];
        h8 bf1 = *(const h8*)&wp[(((w * 2 + 1) * 4 + kc) * 64 + lane) * 8];
        h8 af[4];
#pragma unroll
        for (int rt = 0; rt < 4; ++rt)
            af[rt] = *(const h8*)&Afr[((rt * 4 + kc) * 64 + lane) * 8];
#pragma unroll
        for (int rt = 0; rt < 4; ++rt)
            acc[rt][0] = __builtin_amdgcn_mfma_f32_16x16x32_f16(af[rt], bf0, acc[rt][0], 0, 0, 0);
#pragma unroll
        for (int rt = 0; rt < 4; ++rt)
            acc[rt][1] = __builtin_amdgcn_mfma_f32_16x16x32_f16(af[rt], bf1, acc[rt][1], 0, 0, 0);
    }
}

__device__ __forceinline__ void vals_to_afrag(_Float16* Afr, const float vals[4][2][4],
                                              int lane, int w) {
    int cl = lane & 15, quad = lane >> 4;
#pragma unroll
    for (int ctl = 0; ctl < 2; ++ctl) {
        int col = (w * 2 + ctl) * 16 + cl;
        int kc = col >> 5, o = (col >> 3) & 3, j = col & 7;
#pragma unroll
        for (int rt = 0; rt < 4; ++rt)
#pragma unroll
            for (int i = 0; i < 4; ++i) {
                int m = quad * 4 + i;
                Afr[((rt * 4 + kc) * 64 + o * 16 + m) * 8 + j] = (_Float16)vals[rt][ctl][i];
            }
    }
}

// stage A = elu(P2[s] + Q2[rv] + b1) for one tile into Afr (round-7 staging)
__device__ __forceinline__ void stage_askip(_Float16* Afr, const float* __restrict__ P2,
                                            const float* __restrict__ Q2,
                                            const float* __restrict__ b1v,
                                            unsigned b, unsigned e0, int lane, int w) {
    int r = lane, kc = w;
    unsigned e = e0 + r;
    unsigned s = e / 63;
    unsigned jj = e - s * 63;
    unsigned rv = jj + (jj >= s ? 1u : 0u);
    const float4* Pr = (const float4*)(P2 + (b * 64 + s) * 128);
    const float4* Qr = (const float4*)(Q2 + (b * 64 + rv) * 128);
    const float4* B1 = (const float4*)b1v;
    int rt = r >> 4, m = r & 15;
#pragma unroll
    for (int o = 0; o < 4; ++o) {
        int c4 = kc * 8 + o * 2;
        float4 p0 = Pr[c4], q0 = Qr[c4], bb0 = B1[c4];
        float4 p1 = Pr[c4 + 1], q1 = Qr[c4 + 1], bb1 = B1[c4 + 1];
        h8 v;
        v[0] = (_Float16)elu_f(p0.x + q0.x + bb0.x);
        v[1] = (_Float16)elu_f(p0.y + q0.y + bb0.y);
        v[2] = (_Float16)elu_f(p0.z + q0.z + bb0.z);
        v[3] = (_Float16)elu_f(p0.w + q0.w + bb0.w);
        v[4] = (_Float16)elu_f(p1.x + q1.x + bb1.x);
        v[5] = (_Float16)elu_f(p1.y + q1.y + bb1.y);
        v[6] = (_Float16)elu_f(p1.z + q1.z + bb1.z);
        v[7] = (_Float16)elu_f(p1.w + q1.w + bb1.w);
        *(h8*)&Afr[((rt * 4 + kc) * 64 + o * 16 + m) * 8] = v;
    }
}

// ---------------------------------------------------------------------------
// Kernels
// ---------------------------------------------------------------------------

__global__ void k_zero3(float* W) {
    int i = blockIdx.x * 256 + threadIdx.x;
    if (i < 16384) W[OFF_P2 + i] = 0.f;
    else if (i < 32768) W[OFF_P4 + i - 16384] = 0.f;
    else if (i < 49152) W[OFF_Q4 + i - 32768] = 0.f;
    else if (i < 49280) W[OFF_CVEC + i - 49152] = 0.f;
}

__global__ void k_finalize(const float* __restrict__ sums, float* __restrict__ coef,
                           float invM, const float* __restrict__ g,
                           const float* __restrict__ beta, float* __restrict__ zbuf) {
    int c = threadIdx.x;  // 128
    float s = 0.f, q = 0.f;
#pragma unroll 8
    for (int t = 0; t < 64; ++t) {
        s += sums[t * 256 + c];
        q += sums[t * 256 + 128 + c];
    }
    float mean = s * invM;
    float var = q * invM - mean * mean;
    float a = g[c] * rsqrtf(var + BN_EPS);
    coef[c] = a;
    coef[128 + c] = beta[c] - mean * a;
    if (zbuf)
        for (int i = c; i < 16384; i += 128) zbuf[i] = 0.f;
}

// pack fp32 W[128][128] into MFMA-B fp16 frag layout
__global__ void k_packw(const float* __restrict__ w, _Float16* __restrict__ wp) {
    int flat = blockIdx.x * 256 + threadIdx.x;  // 0..2047
    int g = flat >> 6, L = flat & 63;
    int ct = g >> 2, kc = g & 3;
    int n = ct * 16 + (L & 15), k0 = kc * 32 + (L >> 4) * 8;
    h8 v;
#pragma unroll
    for (int j = 0; j < 8; ++j) v[j] = (_Float16)w[(k0 + j) * 128 + n];
    *(h8*)&wp[flat * 8] = v;
}

// mlp1 (fp32, round-7)
__global__ __launch_bounds__(256) void k_mlp1(const float* __restrict__ x,
                                              const float* __restrict__ w1,
                                              const float* __restrict__ b1,
                                              const float* __restrict__ w2,
                                              const float* __restrict__ b2,
                                              float* __restrict__ h1, float* __restrict__ st) {
    __shared__ float Xs[64 * 44];
    __shared__ float As[64 * 132];
    int tid = threadIdx.x, tx = tid & 15, ty = tid >> 4;
    int r0 = blockIdx.x * 64;
    for (int idx = tid; idx < 64 * 40; idx += 256) {
        int r = idx / 40, k = idx - r * 40;
        int rr = r0 + r, b = rr >> 6, n = rr & 63, t = k >> 2, d = k & 3;
        Xs[r * 44 + k] = x[((b * 10 + t) * 64 + n) * 4 + d];
    }
    __syncthreads();
    float acc[4][8] = {};
    gemm_globalW(Xs, 44, w1, 40, acc, tx, ty);
    float vals[4][8];
    bias_elu(acc, b1, vals, tx);
    int ca = 4 * tx, cb = 64 + 4 * tx;
#pragma unroll
    for (int j = 0; j < 4; ++j) {
        int r = ty + 16 * j;
#pragma unroll
        for (int u = 0; u < 4; ++u) {
            As[r * 132 + ca + u] = vals[j][u];
            As[r * 132 + cb + u] = vals[j][u + 4];
        }
    }
    __syncthreads();
    float acc2[4][8] = {};
    gemm_globalW(As, 132, w2, 128, acc2, tx, ty);
    float vals2[4][8];
    bias_elu(acc2, b2, vals2, tx);
    store_tile(h1, r0, vals2, tx, ty);
    stats_tail(vals2, As, st + (blockIdx.x & 63) * 256, tid, tx, ty);
}

// P/Q precompute (fp32, round-7)
__global__ __launch_bounds__(256) void k_pq(const float* __restrict__ h,
                                            const float* __restrict__ coef,
                                            const float* __restrict__ w,
                                            float* __restrict__ P, float* __restrict__ Q) {
    __shared__ float As[64 * 132];
    int tid = threadIdx.x, tx = tid & 15, ty = tid >> 4;
    int half = blockIdx.x >> 6;
    int r0 = (blockIdx.x & 63) * 64;
    const float* Wg = w + half * 128 * 128;
    float* out = half ? Q : P;
    const float4* h4 = (const float4*)h;
    const float4* av = (const float4*)coef;
    const float4* cv = (const float4*)(coef + 128);
#pragma unroll
    for (int i = 0; i < 8; ++i) {
        int f4 = tid + i * 256;
        int r = f4 >> 5, c4 = f4 & 31;
        float4 hv = h4[(r0 + r) * 32 + c4];
        float4 a = av[c4], c = cv[c4];
        float4 v;
        v.x = a.x * hv.x + c.x;
        v.y = a.y * hv.y + c.y;
        v.z = a.z * hv.z + c.z;
        v.w = a.w * hv.w + c.w;
        *(float4*)(As + r * 132 + c4 * 4) = v;
    }
    __syncthreads();
    float acc[4][8] = {};
    gemm_globalW(As, 132, Wg, 128, acc, tx, ty);
#pragma unroll
    for (int j = 0; j < 4; ++j) {
        int r = r0 + ty + 16 * j;
        *(float4*)(out + r * 128 + 4 * tx) = make_float4(acc[j][0], acc[j][1], acc[j][2], acc[j][3]);
        *(float4*)(out + r * 128 + 64 + 4 * tx) = make_float4(acc[j][4], acc[j][5], acc[j][6], acc[j][7]);
    }
}

// Recv-major fused mlp2 + edge2node (round-7 proven)
__global__ __launch_bounds__(256, 8) void k_mlp2agg(const float* __restrict__ P2,
                                                    const float* __restrict__ Q2,
                                                    const float* __restrict__ b1,
                                                    const _Float16* __restrict__ w2p,
                                                    const float* __restrict__ b2,
                                                    float* __restrict__ aggraw,
                                                    float* __restrict__ st) {
    __shared__ _Float16 Afr[8192];  // 16 KB
    int tid = threadIdx.x;
    int lane = tid & 63, w = tid >> 6;
    int b = blockIdx.x >> 6, n = blockIdx.x & 63;
    float* stc = st + (blockIdx.x & 63) * 256;
    {
        int r = lane, kc = w;
        int s = (r < 63) ? (r + (r >= n ? 1 : 0)) : n;  // row 63: dummy
        const float4* Pr = (const float4*)(P2 + (b * 64 + s) * 128);
        const float4* Qr = (const float4*)(Q2 + (b * 64 + n) * 128);
        const float4* B1 = (const float4*)b1;
        int rt = r >> 4, m = r & 15;
#pragma unroll
        for (int o = 0; o < 4; ++o) {
            int c4 = kc * 8 + o * 2;
            float4 p0 = Pr[c4], q0 = Qr[c4], bb0 = B1[c4];
            float4 p1 = Pr[c4 + 1], q1 = Qr[c4 + 1], bb1 = B1[c4 + 1];
            h8 v;
            v[0] = (_Float16)elu_f(p0.x + q0.x + bb0.x);
            v[1] = (_Float16)elu_f(p0.y + q0.y + bb0.y);
            v[2] = (_Float16)elu_f(p0.z + q0.z + bb0.z);
            v[3] = (_Float16)elu_f(p0.w + q0.w + bb0.w);
            v[4] = (_Float16)elu_f(p1.x + q1.x + bb1.x);
            v[5] = (_Float16)elu_f(p1.y + q1.y + bb1.y);
            v[6] = (_Float16)elu_f(p1.z + q1.z + bb1.z);
            v[7] = (_Float16)elu_f(p1.w + q1.w + bb1.w);
            *(h8*)&Afr[((rt * 4 + kc) * 64 + o * 16 + m) * 8] = v;
        }
    }
    __syncthreads();
    f4v acc[4][2];
#pragma unroll
    for (int rt = 0; rt < 4; ++rt)
#pragma unroll
        for (int c = 0; c < 2; ++c) acc[rt][c] = (f4v){0.f, 0.f, 0.f, 0.f};
    mfma_gemm_gw(Afr, w2p, acc, lane, w);
    int cl = lane & 15, quad = lane >> 4;
#pragma unroll
    for (int ctl = 0; ctl < 2; ++ctl) {
        int col = (w * 2 + ctl) * 16 + cl;
        float bias = b2[col];
        float s1 = 0.f, s2 = 0.f;
#pragma unroll
        for (int rt = 0; rt < 4; ++rt)
#pragma unroll
            for (int i = 0; i < 4; ++i) {
                int row = rt * 16 + quad * 4 + i;
                float v = elu_f(acc[rt][ctl][i] + bias);
                if (row == 63) v = 0.f;
                s1 += v;
                s2 += v * v;
            }
        s1 += __shfl_xor(s1, 16);
        s2 += __shfl_xor(s2, 16);
        s1 += __shfl_xor(s1, 32);
        s2 += __shfl_xor(s2, 32);
        if (quad == 0) {
            aggraw[(b * 64 + n) * 128 + col] = s1;
            atomicAdd(stc + col, s1);
            atomicAdd(stc + 128 + col, s2);
        }
    }
}

// prep for mlp4 skip path (round-7)
__global__ void k_wcprep(const float* __restrict__ w41, const float* __restrict__ coef2,
                         _Float16* __restrict__ wcp, float* __restrict__ cvec) {
    int k = blockIdx.x, c = threadIdx.x;  // 128 x 128
    float wv = w41[(256 + k) * 128 + c];
    int g = (c >> 4) * 4 + (k >> 5);
    int L = ((k >> 3) & 3) * 16 + (c & 15);
    int j = k & 7;
    wcp[(g * 64 + L) * 8 + j] = (_Float16)(coef2[k] * wv);
    atomicAdd(&cvec[c], coef2[128 + k] * wv);
}

// mlp3 (fp32, round-7)
__global__ __launch_bounds__(256) void k_mlp3(const float* __restrict__ raw,
                                              const float* __restrict__ coef2,
                                              const float* __restrict__ w1,
                                              const float* __restrict__ b1,
                                              const float* __restrict__ w2,
                                              const float* __restrict__ b2,
                                              float* __restrict__ h3, float* __restrict__ st) {
    __shared__ float As[64 * 132];
    int tid = threadIdx.x, tx = tid & 15, ty = tid >> 4;
    int r0 = blockIdx.x * 64;
    const float4* in4 = (const float4*)raw;
    const float4* av = (const float4*)coef2;
    const float4* cv = (const float4*)(coef2 + 128);
    const float inv63 = 1.f / 63.f;
#pragma unroll
    for (int i = 0; i < 8; ++i) {
        int f4 = tid + i * 256;
        int r = f4 >> 5, c4 = f4 & 31;
        float4 hv = in4[(r0 + r) * 32 + c4];
        float4 a = av[c4], c = cv[c4];
        float4 v;
        v.x = a.x * hv.x * inv63 + c.x;
        v.y = a.y * hv.y * inv63 + c.y;
        v.z = a.z * hv.z * inv63 + c.z;
        v.w = a.w * hv.w * inv63 + c.w;
        *(float4*)(As + r * 132 + c4 * 4) = v;
    }
    __syncthreads();
    float acc[4][8] = {};
    gemm_globalW(As, 132, w1, 128, acc, tx, ty);
    float vals[4][8];
    bias_elu(acc, b1, vals, tx);
    __syncthreads();
    int ca = 4 * tx, cb = 64 + 4 * tx;
#pragma unroll
    for (int j = 0; j < 4; ++j) {
        int r = ty + 16 * j;
#pragma unroll
        for (int u = 0; u < 4; ++u) {
            As[r * 132 + ca + u] = vals[j][u];
            As[r * 132 + cb + u] = vals[j][u + 4];
        }
    }
    __syncthreads();
    float acc2[4][8] = {};
    gemm_globalW(As, 132, w2, 128, acc2, tx, ty);
    float vals2[4][8];
    bias_elu(acc2, b2, vals2, tx);
    store_tile(h3, r0, vals2, tx, ty);
    stats_tail(vals2, As, st + (blockIdx.x & 63) * 256, tid, tx, ty);
}

// mlp4 edge kernel: TWO 64-row tiles per block. Each weight fragment is loaded
// once and feeds both tiles' MFMAs (gemm2_gw); two independent dependency
// chains per wave hide latency. ep2 = direct P4/Q4 gathers (round-4-proven).
// Stats: per-column shfl reduce over both tiles -> one atomic pair.
__global__ __launch_bounds__(256, 3) void k_mlp4r(const float* __restrict__ P2,
                                                  const float* __restrict__ Q2,
                                                  const float* __restrict__ m2b1,
                                                  const _Float16* __restrict__ w2p2,
                                                  const float* __restrict__ m2b2,
                                                  const float* __restrict__ P4,
                                                  const float* __restrict__ Q4,
                                                  const _Float16* __restrict__ wcp,
                                                  const float* __restrict__ cvec,
                                                  const float* __restrict__ b1,
                                                  const _Float16* __restrict__ w4p2,
                                                  const float* __restrict__ b2,
                                                  unsigned short* __restrict__ h4,
                                                  float* __restrict__ st) {
    __shared__ _Float16 Afr0[8192];  // 16 KB (tile 0; reused as bf16 bounce)
    __shared__ _Float16 Afr1[8192];  // 16 KB (tile 1)
    int tid = threadIdx.x;
    int lane = tid & 63, w = tid >> 6, cl = lane & 15, quad = lane >> 4;
    unsigned t0 = 2u * blockIdx.x, t1 = t0 + 1u;
    unsigned b0 = t0 / 63, b1i = t1 / 63;
    unsigned e00 = (t0 - b0 * 63) * 64, e01 = (t1 - b1i * 63) * 64;
    int row00 = t0 * 64, row01 = t1 * 64;
    float* stc = st + (blockIdx.x & 63) * 256;
    // staging both tiles
    stage_askip(Afr0, P2, Q2, m2b1, b0, e00, lane, w);
    stage_askip(Afr1, P2, Q2, m2b1, b1i, e01, lane, w);
    __syncthreads();
    f4v acc0[4][2], acc1[4][2];
#pragma unroll
    for (int rt = 0; rt < 4; ++rt)
#pragma unroll
        for (int c = 0; c < 2; ++c) {
            acc0[rt][c] = (f4v){0.f, 0.f, 0.f, 0.f};
            acc1[rt][c] = (f4v){0.f, 0.f, 0.f, 0.f};
        }
    gemm2_gw(Afr0, Afr1, w2p2, acc0, acc1, lane, w);
    // ep1: h2 = elu(acc + m2b2[col]) for both tiles
    float v0[4][2][4], v1[4][2][4];
#pragma unroll
    for (int ctl = 0; ctl < 2; ++ctl) {
        float bias = m2b2[(w * 2 + ctl) * 16 + cl];
#pragma unroll
        for (int rt = 0; rt < 4; ++rt)
#pragma unroll
            for (int i = 0; i < 4; ++i) {
                v0[rt][ctl][i] = elu_f(acc0[rt][ctl][i] + bias);
                v1[rt][ctl][i] = elu_f(acc1[rt][ctl][i] + bias);
            }
    }
    __syncthreads();
    vals_to_afrag(Afr0, v0, lane, w);
    vals_to_afrag(Afr1, v1, lane, w);
    __syncthreads();
#pragma unroll
    for (int rt = 0; rt < 4; ++rt)
#pragma unroll
        for (int c = 0; c < 2; ++c) {
            acc0[rt][c] = (f4v){0.f, 0.f, 0.f, 0.f};
            acc1[rt][c] = (f4v){0.f, 0.f, 0.f, 0.f};
        }
    gemm2_gw(Afr0, Afr1, wcp, acc0, acc1, lane, w);
    // ep2: pre1 = elu(acc + P4[s][col] + Q4[rv][col] + b1[col] + cvec[col])
    {
        int col0 = w * 32 + cl, col1 = col0 + 16;
        float base0 = b1[col0] + cvec[col0];
        float base1 = b1[col1] + cvec[col1];
#pragma unroll
        for (int rt = 0; rt < 4; ++rt)
#pragma unroll
            for (int i = 0; i < 4; ++i) {
                int rr = rt * 16 + quad * 4 + i;
                {
                    unsigned e = e00 + rr;
                    unsigned s = e / 63;
                    unsigned jj = e - s * 63;
                    unsigned rv = jj + (jj >= s ? 1u : 0u);
                    const float* Pr = P4 + (b0 * 64 + s) * 128;
                    const float* Qr = Q4 + (b0 * 64 + rv) * 128;
                    v0[rt][0][i] = elu_f(acc0[rt][0][i] + Pr[col0] + Qr[col0] + base0);
                    v0[rt][1][i] = elu_f(acc0[rt][1][i] + Pr[col1] + Qr[col1] + base1);
                }
                {
                    unsigned e = e01 + rr;
                    unsigned s = e / 63;
                    unsigned jj = e - s * 63;
                    unsigned rv = jj + (jj >= s ? 1u : 0u);
                    const float* Pr = P4 + (b1i * 64 + s) * 128;
                    const float* Qr = Q4 + (b1i * 64 + rv) * 128;
                    v1[rt][0][i] = elu_f(acc1[rt][0][i] + Pr[col0] + Qr[col0] + base0);
                    v1[rt][1][i] = elu_f(acc1[rt][1][i] + Pr[col1] + Qr[col1] + base1);
                }
            }
    }
    __syncthreads();
    vals_to_afrag(Afr0, v0, lane, w);
    vals_to_afrag(Afr1, v1, lane, w);
    __syncthreads();
#pragma unroll
    for (int rt = 0; rt < 4; ++rt)
#pragma unroll
        for (int c = 0; c < 2; ++c) {
            acc0[rt][c] = (f4v){0.f, 0.f, 0.f, 0.f};
            acc1[rt][c] = (f4v){0.f, 0.f, 0.f, 0.f};
        }
    gemm2_gw(Afr0, Afr1, w4p2, acc0, acc1, lane, w);
    // ep3: h4 = elu(acc + b2[col]) both tiles; merged column stats
#pragma unroll
    for (int ctl = 0; ctl < 2; ++ctl) {
        int col = (w * 2 + ctl) * 16 + cl;
        float bias = b2[col];
        float s1 = 0.f, s2 = 0.f;
#pragma unroll
        for (int rt = 0; rt < 4; ++rt)
#pragma unroll
            for (int i = 0; i < 4; ++i) {
                float va = elu_f(acc0[rt][ctl][i] + bias);
                float vb = elu_f(acc1[rt][ctl][i] + bias);
                v0[rt][ctl][i] = va;
                v1[rt][ctl][i] = vb;
                s1 += va + vb;
                s2 += va * va + vb * vb;
            }
        s1 += __shfl_xor(s1, 16);
        s2 += __shfl_xor(s2, 16);
        s1 += __shfl_xor(s1, 32);
        s2 += __shfl_xor(s2, 32);
        if (quad == 0) {
            atomicAdd(stc + col, s1);
            atomicAdd(stc + 128 + col, s2);
        }
    }
    __syncthreads();  // GEMM3 A-frag reads done; reuse Afr as bf16 tiles
    unsigned short* T0 = (unsigned short*)Afr0;
    unsigned short* T1 = (unsigned short*)Afr1;
#pragma unroll
    for (int ctl = 0; ctl < 2; ++ctl) {
        int col = (w * 2 + ctl) * 16 + cl;
#pragma unroll
        for (int rt = 0; rt < 4; ++rt)
#pragma unroll
            for (int i = 0; i < 4; ++i) {
                int rr = rt * 16 + quad * 4 + i;
                T0[rr * 128 + col] = bf16r(v0[rt][ctl][i]);
                T1[rr * 128 + col] = bf16r(v1[rt][ctl][i]);
            }
    }
    __syncthreads();
    {
        int rr = tid >> 2, cq = tid & 3;
#pragma unroll
        for (int i = 0; i < 4; ++i) {
            int off = rr * 128 + cq * 32 + i * 8;
            *(uint4*)(h4 + (size_t)row00 * 128 + off) = *(uint4*)&T0[off];
            *(uint4*)(h4 + (size_t)row01 * 128 + off) = *(uint4*)&T1[off];
        }
    }
}

// final: out[row,k] = sum_c (a4[c]*h4[row,c]+shift4[c]) * fcw[c,k] + fcb[k]
__global__ __launch_bounds__(256) void k_out(const unsigned short* __restrict__ h4,
                                             const float* __restrict__ coef4,
                                             const float* __restrict__ fcw,
                                             const float* __restrict__ fcb,
                                             float* __restrict__ out) {
    int tid = threadIdx.x;
    int lane = tid & 31, rsub = tid >> 5;
    int row = blockIdx.x * 8 + rsub;
    uint2 u = ((const uint2*)(h4 + (size_t)row * 128))[lane];
    float x0 = __uint_as_float(u.x << 16);
    float x1 = __uint_as_float(u.x & 0xffff0000u);
    float x2 = __uint_as_float(u.y << 16);
    float x3 = __uint_as_float(u.y & 0xffff0000u);
    float4 a = ((const float4*)coef4)[lane];
    float4 c = ((const float4*)(coef4 + 128))[lane];
    x0 = a.x * x0 + c.x;
    x1 = a.y * x1 + c.y;
    x2 = a.z * x2 + c.z;
    x3 = a.w * x3 + c.w;
    const float4* W = (const float4*)(fcw + lane * 8);
    float4 w01 = W[0], w23 = W[1];
    float s0 = x0 * w01.x + x1 * w01.z + x2 * w23.x + x3 * w23.z;
    float s1 = x0 * w01.y + x1 * w01.w + x2 * w23.y + x3 * w23.w;
#pragma unroll
    for (int off = 16; off > 0; off >>= 1) {
        s0 += __shfl_down(s0, off, 32);
        s1 += __shfl_down(s1, off, 32);
    }
    if (lane == 0) {
        out[row * 2] = s0 + fcb[0];
        out[row * 2 + 1] = s1 + fcb[1];
    }
}

// ---------------------------------------------------------------------------

extern "C" void kernel_launch(void* const* d_in, const int* in_sizes, int n_in,
                              void* d_out, int out_size, void* d_ws, size_t ws_size,
                              hipStream_t stream) {
    const float* x = (const float*)d_in[0];
    const float* m1_w1 = (const float*)d_in[1];
    const float* m1_b1 = (const float*)d_in[2];
    const float* m1_w2 = (const float*)d_in[3];
    const float* m1_b2 = (const float*)d_in[4];
    const float* m1_g = (const float*)d_in[5];
    const float* m1_be = (const float*)d_in[6];
    const float* m2_w1 = (const float*)d_in[7];
    const float* m2_b1 = (const float*)d_in[8];
    const float* m2_w2 = (const float*)d_in[9];
    const float* m2_b2 = (const float*)d_in[10];
    const float* m2_g = (const float*)d_in[11];
    const float* m2_be = (const float*)d_in[12];
    const float* m3_w1 = (const float*)d_in[13];
    const float* m3_b1 = (const float*)d_in[14];
    const float* m3_w2 = (const float*)d_in[15];
    const float* m3_b2 = (const float*)d_in[16];
    const float* m3_g = (const float*)d_in[17];
    const float* m3_be = (const float*)d_in[18];
    const float* m4_w1 = (const float*)d_in[19];
    const float* m4_b1 = (const float*)d_in[20];
    const float* m4_w2 = (const float*)d_in[21];
    const float* m4_b2 = (const float*)d_in[22];
    const float* m4_g = (const float*)d_in[23];
    const float* m4_be = (const float*)d_in[24];
    const float* fc_w = (const float*)d_in[25];
    const float* fc_b = (const float*)d_in[26];
    float* out = (float*)d_out;

    float* W = (float*)d_ws;
    float* coef1 = W + OFF_COEF;
    float* coef2 = W + OFF_COEF + 256;
    float* coef3 = W + OFF_COEF + 512;
    float* coef4 = W + OFF_COEF + 768;
    float* cvec = W + OFF_CVEC;
    float* h1 = W + OFF_H1;        // aliased: aggraw; sums4 = h1[0:16384)
    float* aggraw = h1;
    float* sums4 = h1;
    float* P2 = W + OFF_P2;        // sums1 = P2[0:16384)
    float* sums1 = P2;
    float* Q2 = W + OFF_Q2;
    float* h3 = W + OFF_H3;
    float* P4 = W + OFF_P4;        // sums2 = P4[0:16384)
    float* sums2 = P4;
    float* Q4 = W + OFF_Q4;        // sums3 = Q4[0:16384)
    float* sums3 = Q4;
    _Float16* w2p2 = (_Float16*)(W + OFF_W2P);
    _Float16* w4p2 = (_Float16*)(W + OFF_W4P);
    _Float16* wcp = (_Float16*)(W + OFF_WCP);
    unsigned short* h4b = (unsigned short*)(W + OFF_H4B);

    if (ws_size < WS_BYTES) return;  // safe-fail diagnostic (no OOB fault)

    k_zero3<<<193, 256, 0, stream>>>(W);
    k_packw<<<8, 256, 0, stream>>>(m2_w2, w2p2);
    k_packw<<<8, 256, 0, stream>>>(m4_w2, w4p2);
    k_mlp1<<<64, 256, 0, stream>>>(x, m1_w1, m1_b1, m1_w2, m1_b2, h1, sums1);
    k_finalize<<<1, 128, 0, stream>>>(sums1, coef1, 1.f / 4096.f, m1_g, m1_be, nullptr);
    k_pq<<<128, 256, 0, stream>>>(h1, coef1, m2_w1, P2, Q2);
    k_mlp2agg<<<4096, 256, 0, stream>>>(P2, Q2, m2_b1, w2p2, m2_b2, aggraw, sums2);
    k_finalize<<<1, 128, 0, stream>>>(sums2, coef2, 1.f / 258048.f, m2_g, m2_be, nullptr);
    k_wcprep<<<128, 128, 0, stream>>>(m4_w1, coef2, wcp, cvec);
    k_mlp3<<<64, 256, 0, stream>>>(aggraw, coef2, m3_w1, m3_b1, m3_w2, m3_b2, h3, sums3);
    k_finalize<<<1, 128, 0, stream>>>(sums3, coef3, 1.f / 4096.f, m3_g, m3_be, sums4);
    k_pq<<<128, 256, 0, stream>>>(h3, coef3, m4_w1, P4, Q4);
    k_mlp4r<<<2016, 256, 0, stream>>>(P2, Q2, m2_b1, w2p2, m2_b2, P4, Q4, wcp, cvec,
                                      m4_b1, w4p2, m4_b2, h4b, sums4);
    k_finalize<<<1, 128, 0, stream>>>(sums4, coef4, 1.f / 258048.f, m4_g, m4_be, nullptr);
    k_out<<<32256, 256, 0, stream>>>(h4b, coef4, fc_w, fc_b, out);
}

// Round 11
// 349.031 us; speedup vs baseline: 1.3017x; 1.0688x over previous
//
#include <hip/hip_runtime.h>

#define BN_EPS 1e-5f

using h8 = __attribute__((ext_vector_type(8))) _Float16;
using f4v = __attribute__((ext_vector_type(4))) float;

// workspace float offsets (round-7/10 proven layout)
#define OFF_COEF 0        // 4 stages x 256 (a @ [0:128), shift @ [128:256))
#define OFF_CVEC 1024     // 128
#define OFF_H1 4096       // 4096x128 (aliased: aggraw; first 16384 = sums4)
#define OFF_P2 528384     // first 16384 floats = sums1 (dead until k_pq1)
#define OFF_Q2 1052672
#define OFF_H3 1576960
#define OFF_P4 2101248    // first 16384 = sums2 (dead until k_pq4)
#define OFF_Q4 2625536    // first 16384 = sums3 (dead until k_pq4)
#define OFF_W2P 3149824   // 16384 fp16 = 8192 floats each
#define OFF_W4P 3158016
#define OFF_WCP 3166208
#define OFF_H4B 3174400   // 258048x128 16-bit: h2 (fp16) then h4 (bf16) in place
#define WS_BYTES 78757888ull

__device__ __forceinline__ float elu_f(float x) {
    return x > 0.f ? x : __expf(x) - 1.f;
}

__device__ __forceinline__ unsigned short bf16r(float x) {
    unsigned u = __float_as_uint(x);
    return (unsigned short)((u + 0x7fffu + ((u >> 16) & 1u)) >> 16);
}

// ---------------------------------------------------------------------------
// fp32 tile GEMM helpers (node-level kernels) - proven.
// ---------------------------------------------------------------------------

__device__ __forceinline__ void gemm_acc(float acc[4][8], float a0, float a1, float a2,
                                         float a3, const float4 wa, const float4 wb) {
    const float w[8] = {wa.x, wa.y, wa.z, wa.w, wb.x, wb.y, wb.z, wb.w};
    const float a[4] = {a0, a1, a2, a3};
#pragma unroll
    for (int j = 0; j < 4; ++j)
#pragma unroll
        for (int u = 0; u < 8; ++u)
            acc[j][u] = fmaf(a[j], w[u], acc[j][u]);
}

__device__ __forceinline__ void gemm_globalW(const float* As, int lda,
                                             const float* __restrict__ Wg, int K,
                                             float acc[4][8], int tx, int ty) {
    const float4* Wg4 = (const float4*)Wg;
#pragma unroll 4
    for (int k = 0; k < K; ++k) {
        float a0 = As[ty * lda + k];
        float a1 = As[(ty + 16) * lda + k];
        float a2 = As[(ty + 32) * lda + k];
        float a3 = As[(ty + 48) * lda + k];
        float4 wa = Wg4[k * 32 + tx];
        float4 wb = Wg4[k * 32 + 16 + tx];
        gemm_acc(acc, a0, a1, a2, a3, wa, wb);
    }
}

__device__ __forceinline__ void bias_elu(const float acc[4][8], const float* __restrict__ bias,
                                         float vals[4][8], int tx) {
    int ca = 4 * tx, cb = 64 + 4 * tx;
    float bv[8] = {bias[ca], bias[ca + 1], bias[ca + 2], bias[ca + 3],
                   bias[cb], bias[cb + 1], bias[cb + 2], bias[cb + 3]};
#pragma unroll
    for (int j = 0; j < 4; ++j)
#pragma unroll
        for (int u = 0; u < 8; ++u)
            vals[j][u] = elu_f(acc[j][u] + bv[u]);
}

__device__ __forceinline__ void store_tile(float* __restrict__ out, int row0,
                                           const float vals[4][8], int tx, int ty) {
#pragma unroll
    for (int j = 0; j < 4; ++j) {
        int r = row0 + ty + 16 * j;
        *(float4*)(out + r * 128 + 4 * tx) =
            make_float4(vals[j][0], vals[j][1], vals[j][2], vals[j][3]);
        *(float4*)(out + r * 128 + 64 + 4 * tx) =
            make_float4(vals[j][4], vals[j][5], vals[j][6], vals[j][7]);
    }
}

__device__ __forceinline__ void stats_tail(const float vals[4][8], float* red,
                                           float* __restrict__ st, int tid, int tx, int ty) {
    float ls[8], lq[8];
#pragma unroll
    for (int u = 0; u < 8; ++u) {
        ls[u] = vals[0][u] + vals[1][u] + vals[2][u] + vals[3][u];
        lq[u] = vals[0][u] * vals[0][u] + vals[1][u] * vals[1][u] +
                vals[2][u] * vals[2][u] + vals[3][u] * vals[3][u];
    }
    __syncthreads();
    int ca = 4 * tx, cb = 64 + 4 * tx;
#pragma unroll
    for (int u = 0; u < 4; ++u) {
        red[ty * 128 + ca + u] = ls[u];
        red[2048 + ty * 128 + ca + u] = lq[u];
        red[ty * 128 + cb + u] = ls[u + 4];
        red[2048 + ty * 128 + cb + u] = lq[u + 4];
    }
    __syncthreads();
    if (tid < 128) {
        float s = 0.f, q = 0.f;
#pragma unroll
        for (int t = 0; t < 16; ++t) {
            s += red[t * 128 + tid];
            q += red[2048 + t * 128 + tid];
        }
        atomicAdd(st + tid, s);
        atomicAdd(st + 128 + tid, q);
    }
}

// ---------------------------------------------------------------------------
// MFMA helpers (proven). A-frag LDS layout:
// Afr[((rt*4+kc)*64 + o*16 + m)*8 + j] = act[rt*16+m][kc*32+o*8+j] (fp16).
// Weights prepacked in GLOBAL: Wp[((ct*4+kc)*64+L)*8+j] =
// W[kc*32+(L>>4)*8+j][ct*16+(L&15)]. Wave w computes rows 0..63 x cols
// [32w, 32w+32). gemm2_gw: one weight-frag load feeds BOTH tiles' MFMAs.
// ---------------------------------------------------------------------------

__device__ __forceinline__ void gemm2_gw(const _Float16* A0, const _Float16* A1,
                                         const _Float16* __restrict__ wp,
                                         f4v acc0[4][2], f4v acc1[4][2], int lane, int w) {
#pragma unroll
    for (int kc = 0; kc < 4; ++kc) {
        h8 bf0 = *(const h8*)&wp[(((w * 2 + 0) * 4 + kc) * 64 + lane) * 8];
        h8 bf1 = *(const h8*)&wp[(((w * 2 + 1) * 4 + kc) * 64 + lane) * 8];
        h8 af0[4], af1[4];
#pragma unroll
        for (int rt = 0; rt < 4; ++rt) {
            af0[rt] = *(const h8*)&A0[((rt * 4 + kc) * 64 + lane) * 8];
            af1[rt] = *(const h8*)&A1[((rt * 4 + kc) * 64 + lane) * 8];
        }
#pragma unroll
        for (int rt = 0; rt < 4; ++rt) {
            acc0[rt][0] = __builtin_amdgcn_mfma_f32_16x16x32_f16(af0[rt], bf0, acc0[rt][0], 0, 0, 0);
            acc1[rt][0] = __builtin_amdgcn_mfma_f32_16x16x32_f16(af1[rt], bf0, acc1[rt][0], 0, 0, 0);
        }
#pragma unroll
        for (int rt = 0; rt < 4; ++rt) {
            acc0[rt][1] = __builtin_amdgcn_mfma_f32_16x16x32_f16(af0[rt], bf1, acc0[rt][1], 0, 0, 0);
            acc1[rt][1] = __builtin_amdgcn_mfma_f32_16x16x32_f16(af1[rt], bf1, acc1[rt][1], 0, 0, 0);
        }
    }
}

__device__ __forceinline__ void mfma_gemm_gw(const _Float16* Afr,
                                             const _Float16* __restrict__ wp,
                                             f4v acc[4][2], int lane, int w) {
#pragma unroll
    for (int kc = 0; kc < 4; ++kc) {
        h8 bf0 = *(const h8*)&wp[(((w * 2 + 0) * 4 + kc) * 64 + lane) * 8];
        h8 bf1 = *(const h8*)&wp[(((w * 2 + 1) * 4 + kc) * 64 + lane) * 8];
        h8 af[4];
#pragma unroll
        for (int rt = 0; rt < 4; ++rt)
            af[rt] = *(const h8*)&Afr[((rt * 4 + kc) * 64 + lane) * 8];
#pragma unroll
        for (int rt = 0; rt < 4; ++rt)
            acc[rt][0] = __builtin_amdgcn_mfma_f32_16x16x32_f16(af[rt], bf0, acc[rt][0], 0, 0, 0);
#pragma unroll
        for (int rt = 0; rt < 4; ++rt)
            acc[rt][1] = __builtin_amdgcn_mfma_f32_16x16x32_f16(af[rt], bf1, acc[rt][1], 0, 0, 0);
    }
}

__device__ __forceinline__ void vals_to_afrag(_Float16* Afr, const float vals[4][2][4],
                                              int lane, int w) {
    int cl = lane & 15, quad = lane >> 4;
#pragma unroll
    for (int ctl = 0; ctl < 2; ++ctl) {
        int col = (w * 2 + ctl) * 16 + cl;
        int kc = col >> 5, o = (col >> 3) & 3, j = col & 7;
#pragma unroll
        for (int rt = 0; rt < 4; ++rt)
#pragma unroll
            for (int i = 0; i < 4; ++i) {
                int m = quad * 4 + i;
                Afr[((rt * 4 + kc) * 64 + o * 16 + m) * 8 + j] = (_Float16)vals[rt][ctl][i];
            }
    }
}

// ---------------------------------------------------------------------------
// Kernels
// ---------------------------------------------------------------------------

// merged: zero shadow-sum arenas + cvec; pack w2/w4 layer-2 weights to fp16 frag
__global__ void k_prep(float* W, const float* __restrict__ w2src,
                       const float* __restrict__ w4src) {
    int blk = blockIdx.x, tid = threadIdx.x;
    if (blk < 193) {
        int i = blk * 256 + tid;
        if (i < 16384) W[OFF_P2 + i] = 0.f;
        else if (i < 32768) W[OFF_P4 + i - 16384] = 0.f;
        else if (i < 49152) W[OFF_Q4 + i - 32768] = 0.f;
        else if (i < 49280) W[OFF_CVEC + i - 49152] = 0.f;
    } else {
        int second = blk >= 201;
        const float* src = second ? w4src : w2src;
        _Float16* wp = (_Float16*)(W + (second ? OFF_W4P : OFF_W2P));
        int flat = (blk - (second ? 201 : 193)) * 256 + tid;  // 0..2047
        int g = flat >> 6, L = flat & 63;
        int ct = g >> 2, kc = g & 3;
        int nn = ct * 16 + (L & 15), k0 = kc * 32 + (L >> 4) * 8;
        h8 v;
#pragma unroll
        for (int j = 0; j < 8; ++j) v[j] = (_Float16)src[(k0 + j) * 128 + nn];
        *(h8*)&wp[flat * 8] = v;
    }
}

__global__ void k_finalize(const float* __restrict__ sums, float* __restrict__ coef,
                           float invM, const float* __restrict__ g,
                           const float* __restrict__ beta, float* __restrict__ zbuf) {
    int c = threadIdx.x;  // 128
    float s = 0.f, q = 0.f;
#pragma unroll 8
    for (int t = 0; t < 64; ++t) {
        s += sums[t * 256 + c];
        q += sums[t * 256 + 128 + c];
    }
    float mean = s * invM;
    float var = q * invM - mean * mean;
    float a = g[c] * rsqrtf(var + BN_EPS);
    coef[c] = a;
    coef[128 + c] = beta[c] - mean * a;
    if (zbuf)
        for (int i = c; i < 16384; i += 128) zbuf[i] = 0.f;
}

// mlp1 (fp32, proven)
__global__ __launch_bounds__(256) void k_mlp1(const float* __restrict__ x,
                                              const float* __restrict__ w1,
                                              const float* __restrict__ b1,
                                              const float* __restrict__ w2,
                                              const float* __restrict__ b2,
                                              float* __restrict__ h1, float* __restrict__ st) {
    __shared__ float Xs[64 * 44];
    __shared__ float As[64 * 132];
    int tid = threadIdx.x, tx = tid & 15, ty = tid >> 4;
    int r0 = blockIdx.x * 64;
    for (int idx = tid; idx < 64 * 40; idx += 256) {
        int r = idx / 40, k = idx - r * 40;
        int rr = r0 + r, b = rr >> 6, n = rr & 63, t = k >> 2, d = k & 3;
        Xs[r * 44 + k] = x[((b * 10 + t) * 64 + n) * 4 + d];
    }
    __syncthreads();
    float acc[4][8] = {};
    gemm_globalW(Xs, 44, w1, 40, acc, tx, ty);
    float vals[4][8];
    bias_elu(acc, b1, vals, tx);
    int ca = 4 * tx, cb = 64 + 4 * tx;
#pragma unroll
    for (int j = 0; j < 4; ++j) {
        int r = ty + 16 * j;
#pragma unroll
        for (int u = 0; u < 4; ++u) {
            As[r * 132 + ca + u] = vals[j][u];
            As[r * 132 + cb + u] = vals[j][u + 4];
        }
    }
    __syncthreads();
    float acc2[4][8] = {};
    gemm_globalW(As, 132, w2, 128, acc2, tx, ty);
    float vals2[4][8];
    bias_elu(acc2, b2, vals2, tx);
    store_tile(h1, r0, vals2, tx, ty);
    stats_tail(vals2, As, st + (blockIdx.x & 63) * 256, tid, tx, ty);
}

// P/Q precompute (fp32, proven)
__global__ __launch_bounds__(256) void k_pq(const float* __restrict__ h,
                                            const float* __restrict__ coef,
                                            const float* __restrict__ w,
                                            float* __restrict__ P, float* __restrict__ Q) {
    __shared__ float As[64 * 132];
    int tid = threadIdx.x, tx = tid & 15, ty = tid >> 4;
    int half = blockIdx.x >> 6;
    int r0 = (blockIdx.x & 63) * 64;
    const float* Wg = w + half * 128 * 128;
    float* out = half ? Q : P;
    const float4* h4 = (const float4*)h;
    const float4* av = (const float4*)coef;
    const float4* cv = (const float4*)(coef + 128);
#pragma unroll
    for (int i = 0; i < 8; ++i) {
        int f4 = tid + i * 256;
        int r = f4 >> 5, c4 = f4 & 31;
        float4 hv = h4[(r0 + r) * 32 + c4];
        float4 a = av[c4], c = cv[c4];
        float4 v;
        v.x = a.x * hv.x + c.x;
        v.y = a.y * hv.y + c.y;
        v.z = a.z * hv.z + c.z;
        v.w = a.w * hv.w + c.w;
        *(float4*)(As + r * 132 + c4 * 4) = v;
    }
    __syncthreads();
    float acc[4][8] = {};
    gemm_globalW(As, 132, Wg, 128, acc, tx, ty);
#pragma unroll
    for (int j = 0; j < 4; ++j) {
        int r = r0 + ty + 16 * j;
        *(float4*)(out + r * 128 + 4 * tx) = make_float4(acc[j][0], acc[j][1], acc[j][2], acc[j][3]);
        *(float4*)(out + r * 128 + 64 + 4 * tx) = make_float4(acc[j][4], acc[j][5], acc[j][6], acc[j][7]);
    }
}

// Recv-major fused mlp2 + edge2node + h2 MATERIALIZATION. One block per
// (b, recv n); row r -> send s = r+(r>=n) (r=63 dummy, excluded everywhere).
// After stats/agg, bounce h2 to LDS row-major fp16 and scatter-store the 63
// real rows to their edge indices e = s*63 + (s>n ? n : n-1) [round-2-verified
// mapping]. h2 feeds k_mlp4r2 (skip path) so mlp2's GEMM is never recomputed.
__global__ __launch_bounds__(256, 4) void k_mlp2agg(const float* __restrict__ P2,
                                                    const float* __restrict__ Q2,
                                                    const float* __restrict__ b1,
                                                    const _Float16* __restrict__ w2p,
                                                    const float* __restrict__ b2,
                                                    float* __restrict__ aggraw,
                                                    _Float16* __restrict__ h2,
                                                    float* __restrict__ st) {
    __shared__ _Float16 Afr[8192];  // 16 KB; reused as h2 row-major bounce
    int tid = threadIdx.x;
    int lane = tid & 63, w = tid >> 6;
    int b = blockIdx.x >> 6, n = blockIdx.x & 63;
    float* stc = st + (blockIdx.x & 63) * 256;
    {
        int r = lane, kc = w;
        int s = (r < 63) ? (r + (r >= n ? 1 : 0)) : n;  // row 63: dummy
        const float4* Pr = (const float4*)(P2 + (b * 64 + s) * 128);
        const float4* Qr = (const float4*)(Q2 + (b * 64 + n) * 128);
        const float4* B1 = (const float4*)b1;
        int rt = r >> 4, m = r & 15;
#pragma unroll
        for (int o = 0; o < 4; ++o) {
            int c4 = kc * 8 + o * 2;
            float4 p0 = Pr[c4], q0 = Qr[c4], bb0 = B1[c4];
            float4 p1 = Pr[c4 + 1], q1 = Qr[c4 + 1], bb1 = B1[c4 + 1];
            h8 v;
            v[0] = (_Float16)elu_f(p0.x + q0.x + bb0.x);
            v[1] = (_Float16)elu_f(p0.y + q0.y + bb0.y);
            v[2] = (_Float16)elu_f(p0.z + q0.z + bb0.z);
            v[3] = (_Float16)elu_f(p0.w + q0.w + bb0.w);
            v[4] = (_Float16)elu_f(p1.x + q1.x + bb1.x);
            v[5] = (_Float16)elu_f(p1.y + q1.y + bb1.y);
            v[6] = (_Float16)elu_f(p1.z + q1.z + bb1.z);
            v[7] = (_Float16)elu_f(p1.w + q1.w + bb1.w);
            *(h8*)&Afr[((rt * 4 + kc) * 64 + o * 16 + m) * 8] = v;
        }
    }
    __syncthreads();
    f4v acc[4][2];
#pragma unroll
    for (int rt = 0; rt < 4; ++rt)
#pragma unroll
        for (int c = 0; c < 2; ++c) acc[rt][c] = (f4v){0.f, 0.f, 0.f, 0.f};
    mfma_gemm_gw(Afr, w2p, acc, lane, w);
    int cl = lane & 15, quad = lane >> 4;
    float vals[2][4][4];  // [ctl][rt][i]
#pragma unroll
    for (int ctl = 0; ctl < 2; ++ctl) {
        int col = (w * 2 + ctl) * 16 + cl;
        float bias = b2[col];
        float s1 = 0.f, s2 = 0.f;
#pragma unroll
        for (int rt = 0; rt < 4; ++rt)
#pragma unroll
            for (int i = 0; i < 4; ++i) {
                int row = rt * 16 + quad * 4 + i;
                float v = elu_f(acc[rt][ctl][i] + bias);
                if (row == 63) v = 0.f;
                vals[ctl][rt][i] = v;
                s1 += v;
                s2 += v * v;
            }
        s1 += __shfl_xor(s1, 16);
        s2 += __shfl_xor(s2, 16);
        s1 += __shfl_xor(s1, 32);
        s2 += __shfl_xor(s2, 32);
        if (quad == 0) {
            aggraw[(b * 64 + n) * 128 + col] = s1;
            atomicAdd(stc + col, s1);
            atomicAdd(stc + 128 + col, s2);
        }
    }
    __syncthreads();  // GEMM A-frag reads done; reuse Afr as row-major tile
    unsigned short* Tb = (unsigned short*)Afr;
#pragma unroll
    for (int ctl = 0; ctl < 2; ++ctl) {
        int col = (w * 2 + ctl) * 16 + cl;
#pragma unroll
        for (int rt = 0; rt < 4; ++rt)
#pragma unroll
            for (int i = 0; i < 4; ++i) {
                int row = rt * 16 + quad * 4 + i;
                _Float16 hv = (_Float16)vals[ctl][rt][i];
                Tb[row * 128 + col] = *(unsigned short*)&hv;
            }
    }
    __syncthreads();
    {  // scatter 63 real rows to h2[e]: thread t -> row t>>2, 64B quarter t&3
        int rr = tid >> 2, cq = tid & 3;
        if (rr < 63) {
            int s = rr + (rr >= n ? 1 : 0);
            int e = s * 63 + (s > n ? n : n - 1);
            unsigned short* dst = (unsigned short*)h2 + ((size_t)b * 4032 + e) * 128;
#pragma unroll
            for (int i = 0; i < 4; ++i) {
                int off = cq * 32 + i * 8;
                *(uint4*)(dst + off) = *(uint4*)&Tb[rr * 128 + off];
            }
        }
    }
}

// prep for mlp4 skip path (proven)
__global__ void k_wcprep(const float* __restrict__ w41, const float* __restrict__ coef2,
                         _Float16* __restrict__ wcp, float* __restrict__ cvec) {
    int k = blockIdx.x, c = threadIdx.x;  // 128 x 128
    float wv = w41[(256 + k) * 128 + c];
    int g = (c >> 4) * 4 + (k >> 5);
    int L = ((k >> 3) & 3) * 16 + (c & 15);
    int j = k & 7;
    wcp[(g * 64 + L) * 8 + j] = (_Float16)(coef2[k] * wv);
    atomicAdd(&cvec[c], coef2[128 + k] * wv);
}

// mlp3 (fp32, proven)
__global__ __launch_bounds__(256) void k_mlp3(const float* __restrict__ raw,
                                              const float* __restrict__ coef2,
                                              const float* __restrict__ w1,
                                              const float* __restrict__ b1,
                                              const float* __restrict__ w2,
                                              const float* __restrict__ b2,
                                              float* __restrict__ h3, float* __restrict__ st) {
    __shared__ float As[64 * 132];
    int tid = threadIdx.x, tx = tid & 15, ty = tid >> 4;
    int r0 = blockIdx.x * 64;
    const float4* in4 = (const float4*)raw;
    const float4* av = (const float4*)coef2;
    const float4* cv = (const float4*)(coef2 + 128);
    const float inv63 = 1.f / 63.f;
#pragma unroll
    for (int i = 0; i < 8; ++i) {
        int f4 = tid + i * 256;
        int r = f4 >> 5, c4 = f4 & 31;
        float4 hv = in4[(r0 + r) * 32 + c4];
        float4 a = av[c4], c = cv[c4];
        float4 v;
        v.x = a.x * hv.x * inv63 + c.x;
        v.y = a.y * hv.y * inv63 + c.y;
        v.z = a.z * hv.z * inv63 + c.z;
        v.w = a.w * hv.w * inv63 + c.w;
        *(float4*)(As + r * 132 + c4 * 4) = v;
    }
    __syncthreads();
    float acc[4][8] = {};
    gemm_globalW(As, 132, w1, 128, acc, tx, ty);
    float vals[4][8];
    bias_elu(acc, b1, vals, tx);
    __syncthreads();
    int ca = 4 * tx, cb = 64 + 4 * tx;
#pragma unroll
    for (int j = 0; j < 4; ++j) {
        int r = ty + 16 * j;
#pragma unroll
        for (int u = 0; u < 4; ++u) {
            As[r * 132 + ca + u] = vals[j][u];
            As[r * 132 + cb + u] = vals[j][u + 4];
        }
    }
    __syncthreads();
    float acc2[4][8] = {};
    gemm_globalW(As, 132, w2, 128, acc2, tx, ty);
    float vals2[4][8];
    bias_elu(acc2, b2, vals2, tx);
    store_tile(h3, r0, vals2, tx, ty);
    stats_tail(vals2, As, st + (blockIdx.x & 63) * 256, tid, tx, ty);
}

// mlp4 edge kernel v2: h2 is READ (not recomputed). Two 64-row tiles/block.
// Stage h2 tiles coalesced global->LDS A-frag, GEMM2 (wcp skip path), ep2 adds
// P4/Q4 gathers + elu, transform, GEMM3 (w4p2), ep3 + stats + bf16 bounce +
// h4 store IN PLACE over h2 (disjoint tiles per block; read-before-write).
__global__ __launch_bounds__(256, 3) void k_mlp4r2(const _Float16* __restrict__ h2,
                                                   const float* __restrict__ P4,
                                                   const float* __restrict__ Q4,
                                                   const _Float16* __restrict__ wcp,
                                                   const float* __restrict__ cvec,
                                                   const float* __restrict__ b1,
                                                   const _Float16* __restrict__ w4p2,
                                                   const float* __restrict__ b2,
                                                   unsigned short* __restrict__ h4,
                                                   float* __restrict__ st) {
    __shared__ _Float16 Afr0[8192];  // 16 KB (tile 0; reused as bf16 bounce)
    __shared__ _Float16 Afr1[8192];  // 16 KB (tile 1)
    int tid = threadIdx.x;
    int lane = tid & 63, w = tid >> 6, cl = lane & 15, quad = lane >> 4;
    unsigned t0 = 2u * blockIdx.x, t1 = t0 + 1u;
    unsigned b0 = t0 / 63, b1i = t1 / 63;
    unsigned e00 = (t0 - b0 * 63) * 64, e01 = (t1 - b1i * 63) * 64;
    int row00 = t0 * 64, row01 = t1 * 64;
    float* stc = st + (blockIdx.x & 63) * 256;
    // stage h2 tiles: coalesced h8 loads (row-major) -> A-frag LDS
#pragma unroll
    for (int i = 0; i < 4; ++i) {
        int u = tid + i * 256;  // 0..1023
        int r = u >> 4, cu = u & 15;
        int dst = (((r >> 4) * 4 + (cu >> 2)) * 64 + (cu & 3) * 16 + (r & 15)) * 8;
        *(h8*)&Afr0[dst] = *(const h8*)&h2[(size_t)(row00 + r) * 128 + cu * 8];
        *(h8*)&Afr1[dst] = *(const h8*)&h2[(size_t)(row01 + r) * 128 + cu * 8];
    }
    __syncthreads();
    f4v acc0[4][2], acc1[4][2];
#pragma unroll
    for (int rt = 0; rt < 4; ++rt)
#pragma unroll
        for (int c = 0; c < 2; ++c) {
            acc0[rt][c] = (f4v){0.f, 0.f, 0.f, 0.f};
            acc1[rt][c] = (f4v){0.f, 0.f, 0.f, 0.f};
        }
    gemm2_gw(Afr0, Afr1, wcp, acc0, acc1, lane, w);
    // ep2: pre1 = elu(acc + P4[s][col] + Q4[rv][col] + b1[col] + cvec[col])
    float v0[4][2][4], v1[4][2][4];
    {
        int col0 = w * 32 + cl, col1 = col0 + 16;
        float base0 = b1[col0] + cvec[col0];
        float base1 = b1[col1] + cvec[col1];
#pragma unroll
        for (int rt = 0; rt < 4; ++rt)
#pragma unroll
            for (int i = 0; i < 4; ++i) {
                int rr = rt * 16 + quad * 4 + i;
                {
                    unsigned e = e00 + rr;
                    unsigned s = e / 63;
                    unsigned jj = e - s * 63;
                    unsigned rv = jj + (jj >= s ? 1u : 0u);
                    const float* Pr = P4 + (b0 * 64 + s) * 128;
                    const float* Qr = Q4 + (b0 * 64 + rv) * 128;
                    v0[rt][0][i] = elu_f(acc0[rt][0][i] + Pr[col0] + Qr[col0] + base0);
                    v0[rt][1][i] = elu_f(acc0[rt][1][i] + Pr[col1] + Qr[col1] + base1);
                }
                {
                    unsigned e = e01 + rr;
                    unsigned s = e / 63;
                    unsigned jj = e - s * 63;
                    unsigned rv = jj + (jj >= s ? 1u : 0u);
                    const float* Pr = P4 + (b1i * 64 + s) * 128;
                    const float* Qr = Q4 + (b1i * 64 + rv) * 128;
                    v1[rt][0][i] = elu_f(acc1[rt][0][i] + Pr[col0] + Qr[col0] + base0);
                    v1[rt][1][i] = elu_f(acc1[rt][1][i] + Pr[col1] + Qr[col1] + base1);
                }
            }
    }
    __syncthreads();
    vals_to_afrag(Afr0, v0, lane, w);
    vals_to_afrag(Afr1, v1, lane, w);
    __syncthreads();
#pragma unroll
    for (int rt = 0; rt < 4; ++rt)
#pragma unroll
        for (int c = 0; c < 2; ++c) {
            acc0[rt][c] = (f4v){0.f, 0.f, 0.f, 0.f};
            acc1[rt][c] = (f4v){0.f, 0.f, 0.f, 0.f};
        }
    gemm2_gw(Afr0, Afr1, w4p2, acc0, acc1, lane, w);
    // ep3: h4 = elu(acc + b2[col]) both tiles; merged column stats
#pragma unroll
    for (int ctl = 0; ctl < 2; ++ctl) {
        int col = (w * 2 + ctl) * 16 + cl;
        float bias = b2[col];
        float s1 = 0.f, s2 = 0.f;
#pragma unroll
        for (int rt = 0; rt < 4; ++rt)
#pragma unroll
            for (int i = 0; i < 4; ++i) {
                float va = elu_f(acc0[rt][ctl][i] + bias);
                float vb = elu_f(acc1[rt][ctl][i] + bias);
                v0[rt][ctl][i] = va;
                v1[rt][ctl][i] = vb;
                s1 += va + vb;
                s2 += va * va + vb * vb;
            }
        s1 += __shfl_xor(s1, 16);
        s2 += __shfl_xor(s2, 16);
        s1 += __shfl_xor(s1, 32);
        s2 += __shfl_xor(s2, 32);
        if (quad == 0) {
            atomicAdd(stc + col, s1);
            atomicAdd(stc + 128 + col, s2);
        }
    }
    __syncthreads();  // GEMM3 A-frag reads done; reuse Afr as bf16 tiles
    unsigned short* T0 = (unsigned short*)Afr0;
    unsigned short* T1 = (unsigned short*)Afr1;
#pragma unroll
    for (int ctl = 0; ctl < 2; ++ctl) {
        int col = (w * 2 + ctl) * 16 + cl;
#pragma unroll
        for (int rt = 0; rt < 4; ++rt)
#pragma unroll
            for (int i = 0; i < 4; ++i) {
                int rr = rt * 16 + quad * 4 + i;
                T0[rr * 128 + col] = bf16r(v0[rt][ctl][i]);
                T1[rr * 128 + col] = bf16r(v1[rt][ctl][i]);
            }
    }
    __syncthreads();
    {
        int rr = tid >> 2, cq = tid & 3;
#pragma unroll
        for (int i = 0; i < 4; ++i) {
            int off = rr * 128 + cq * 32 + i * 8;
            *(uint4*)(h4 + (size_t)row00 * 128 + off) = *(uint4*)&T0[off];
            *(uint4*)(h4 + (size_t)row01 * 128 + off) = *(uint4*)&T1[off];
        }
    }
}

// final: out[row,k] = sum_c (a4[c]*h4[row,c]+shift4[c]) * fcw[c,k] + fcb[k]
__global__ __launch_bounds__(256) void k_out(const unsigned short* __restrict__ h4,
                                             const float* __restrict__ coef4,
                                             const float* __restrict__ fcw,
                                             const float* __restrict__ fcb,
                                             float* __restrict__ out) {
    int tid = threadIdx.x;
    int lane = tid & 31, rsub = tid >> 5;
    int row = blockIdx.x * 8 + rsub;
    uint2 u = ((const uint2*)(h4 + (size_t)row * 128))[lane];
    float x0 = __uint_as_float(u.x << 16);
    float x1 = __uint_as_float(u.x & 0xffff0000u);
    float x2 = __uint_as_float(u.y << 16);
    float x3 = __uint_as_float(u.y & 0xffff0000u);
    float4 a = ((const float4*)coef4)[lane];
    float4 c = ((const float4*)(coef4 + 128))[lane];
    x0 = a.x * x0 + c.x;
    x1 = a.y * x1 + c.y;
    x2 = a.z * x2 + c.z;
    x3 = a.w * x3 + c.w;
    const float4* W = (const float4*)(fcw + lane * 8);
    float4 w01 = W[0], w23 = W[1];
    float s0 = x0 * w01.x + x1 * w01.z + x2 * w23.x + x3 * w23.z;
    float s1 = x0 * w01.y + x1 * w01.w + x2 * w23.y + x3 * w23.w;
#pragma unroll
    for (int off = 16; off > 0; off >>= 1) {
        s0 += __shfl_down(s0, off, 32);
        s1 += __shfl_down(s1, off, 32);
    }
    if (lane == 0) {
        out[row * 2] = s0 + fcb[0];
        out[row * 2 + 1] = s1 + fcb[1];
    }
}

// ---------------------------------------------------------------------------

extern "C" void kernel_launch(void* const* d_in, const int* in_sizes, int n_in,
                              void* d_out, int out_size, void* d_ws, size_t ws_size,
                              hipStream_t stream) {
    const float* x = (const float*)d_in[0];
    const float* m1_w1 = (const float*)d_in[1];
    const float* m1_b1 = (const float*)d_in[2];
    const float* m1_w2 = (const float*)d_in[3];
    const float* m1_b2 = (const float*)d_in[4];
    const float* m1_g = (const float*)d_in[5];
    const float* m1_be = (const float*)d_in[6];
    const float* m2_w1 = (const float*)d_in[7];
    const float* m2_b1 = (const float*)d_in[8];
    const float* m2_w2 = (const float*)d_in[9];
    const float* m2_b2 = (const float*)d_in[10];
    const float* m2_g = (const float*)d_in[11];
    const float* m2_be = (const float*)d_in[12];
    const float* m3_w1 = (const float*)d_in[13];
    const float* m3_b1 = (const float*)d_in[14];
    const float* m3_w2 = (const float*)d_in[15];
    const float* m3_b2 = (const float*)d_in[16];
    const float* m3_g = (const float*)d_in[17];
    const float* m3_be = (const float*)d_in[18];
    const float* m4_w1 = (const float*)d_in[19];
    const float* m4_b1 = (const float*)d_in[20];
    const float* m4_w2 = (const float*)d_in[21];
    const float* m4_b2 = (const float*)d_in[22];
    const float* m4_g = (const float*)d_in[23];
    const float* m4_be = (const float*)d_in[24];
    const float* fc_w = (const float*)d_in[25];
    const float* fc_b = (const float*)d_in[26];
    float* out = (float*)d_out;

    float* W = (float*)d_ws;
    float* coef1 = W + OFF_COEF;
    float* coef2 = W + OFF_COEF + 256;
    float* coef3 = W + OFF_COEF + 512;
    float* coef4 = W + OFF_COEF + 768;
    float* cvec = W + OFF_CVEC;
    float* h1 = W + OFF_H1;        // aliased: aggraw; sums4 = h1[0:16384)
    float* aggraw = h1;
    float* sums4 = h1;
    float* P2 = W + OFF_P2;        // sums1 = P2[0:16384)
    float* sums1 = P2;
    float* Q2 = W + OFF_Q2;
    float* h3 = W + OFF_H3;
    float* P4 = W + OFF_P4;        // sums2 = P4[0:16384)
    float* sums2 = P4;
    float* Q4 = W + OFF_Q4;        // sums3 = Q4[0:16384)
    float* sums3 = Q4;
    _Float16* w2p2 = (_Float16*)(W + OFF_W2P);
    _Float16* w4p2 = (_Float16*)(W + OFF_W4P);
    _Float16* wcp = (_Float16*)(W + OFF_WCP);
    _Float16* h2f = (_Float16*)(W + OFF_H4B);            // h2 (fp16), then
    unsigned short* h4b = (unsigned short*)(W + OFF_H4B); // h4 (bf16) in place

    if (ws_size < WS_BYTES) return;  // safe-fail diagnostic (no OOB fault)

    k_prep<<<209, 256, 0, stream>>>(W, m2_w2, m4_w2);
    k_mlp1<<<64, 256, 0, stream>>>(x, m1_w1, m1_b1, m1_w2, m1_b2, h1, sums1);
    k_finalize<<<1, 128, 0, stream>>>(sums1, coef1, 1.f / 4096.f, m1_g, m1_be, nullptr);
    k_pq<<<128, 256, 0, stream>>>(h1, coef1, m2_w1, P2, Q2);
    k_mlp2agg<<<4096, 256, 0, stream>>>(P2, Q2, m2_b1, w2p2, m2_b2, aggraw, h2f, sums2);
    k_finalize<<<1, 128, 0, stream>>>(sums2, coef2, 1.f / 258048.f, m2_g, m2_be, nullptr);
    k_wcprep<<<128, 128, 0, stream>>>(m4_w1, coef2, wcp, cvec);
    k_mlp3<<<64, 256, 0, stream>>>(aggraw, coef2, m3_w1, m3_b1, m3_w2, m3_b2, h3, sums3);
    k_finalize<<<1, 128, 0, stream>>>(sums3, coef3, 1.f / 4096.f, m3_g, m3_be, sums4);
    k_pq<<<128, 256, 0, stream>>>(h3, coef3, m4_w1, P4, Q4);
    k_mlp4r2<<<2016, 256, 0, stream>>>(h2f, P4, Q4, wcp, cvec, m4_b1, w4p2, m4_b2,
                                       h4b, sums4);
    k_finalize<<<1, 128, 0, stream>>>(sums4, coef4, 1.f / 258048.f, m4_g, m4_be, nullptr);
    k_out<<<32256, 256, 0, stream>>>(h4b, coef4, fc_w, fc_b, out);
}

// Round 12
// 347.212 us; speedup vs baseline: 1.3085x; 1.0052x over previous
//
#include <hip/hip_runtime.h>

#define BN_EPS 1e-5f

using h8 = __attribute__((ext_vector_type(8))) _Float16;
using h4v = __attribute__((ext_vector_type(4))) _Float16;
using f4v = __attribute__((ext_vector_type(4))) float;

// workspace float offsets (round-7/10/11 proven layout)
#define OFF_COEF 0        // 4 stages x 256 (a @ [0:128), shift @ [128:256))
#define OFF_CVEC 1024     // 128
#define OFF_H1 4096       // 4096x128 (aliased: aggraw; first 16384 = sums4)
#define OFF_P2 528384     // first 16384 floats = sums1 (dead until k_pq1)
#define OFF_Q2 1052672
#define OFF_H3 1576960
#define OFF_P4 2101248    // first 16384 = sums2 (dead until k_pq4)
#define OFF_Q4 2625536    // first 16384 = sums3 (dead until k_pq4)
#define OFF_W2P 3149824   // 16384 fp16 = 8192 floats each
#define OFF_W4P 3158016
#define OFF_WCP 3166208
#define OFF_H4B 3174400   // 258048x128 fp16: h2 then h4 in place
#define WS_BYTES 78757888ull

__device__ __forceinline__ float elu_f(float x) {
    return x > 0.f ? x : __expf(x) - 1.f;
}

// ---------------------------------------------------------------------------
// fp32 tile GEMM helpers (node-level kernels) - proven.
// ---------------------------------------------------------------------------

__device__ __forceinline__ void gemm_acc(float acc[4][8], float a0, float a1, float a2,
                                         float a3, const float4 wa, const float4 wb) {
    const float w[8] = {wa.x, wa.y, wa.z, wa.w, wb.x, wb.y, wb.z, wb.w};
    const float a[4] = {a0, a1, a2, a3};
#pragma unroll
    for (int j = 0; j < 4; ++j)
#pragma unroll
        for (int u = 0; u < 8; ++u)
            acc[j][u] = fmaf(a[j], w[u], acc[j][u]);
}

__device__ __forceinline__ void gemm_globalW(const float* As, int lda,
                                             const float* __restrict__ Wg, int K,
                                             float acc[4][8], int tx, int ty) {
    const float4* Wg4 = (const float4*)Wg;
#pragma unroll 4
    for (int k = 0; k < K; ++k) {
        float a0 = As[ty * lda + k];
        float a1 = As[(ty + 16) * lda + k];
        float a2 = As[(ty + 32) * lda + k];
        float a3 = As[(ty + 48) * lda + k];
        float4 wa = Wg4[k * 32 + tx];
        float4 wb = Wg4[k * 32 + 16 + tx];
        gemm_acc(acc, a0, a1, a2, a3, wa, wb);
    }
}

__device__ __forceinline__ void bias_elu(const float acc[4][8], const float* __restrict__ bias,
                                         float vals[4][8], int tx) {
    int ca = 4 * tx, cb = 64 + 4 * tx;
    float bv[8] = {bias[ca], bias[ca + 1], bias[ca + 2], bias[ca + 3],
                   bias[cb], bias[cb + 1], bias[cb + 2], bias[cb + 3]};
#pragma unroll
    for (int j = 0; j < 4; ++j)
#pragma unroll
        for (int u = 0; u < 8; ++u)
            vals[j][u] = elu_f(acc[j][u] + bv[u]);
}

__device__ __forceinline__ void store_tile(float* __restrict__ out, int row0,
                                           const float vals[4][8], int tx, int ty) {
#pragma unroll
    for (int j = 0; j < 4; ++j) {
        int r = row0 + ty + 16 * j;
        *(float4*)(out + r * 128 + 4 * tx) =
            make_float4(vals[j][0], vals[j][1], vals[j][2], vals[j][3]);
        *(float4*)(out + r * 128 + 64 + 4 * tx) =
            make_float4(vals[j][4], vals[j][5], vals[j][6], vals[j][7]);
    }
}

__device__ __forceinline__ void stats_tail(const float vals[4][8], float* red,
                                           float* __restrict__ st, int tid, int tx, int ty) {
    float ls[8], lq[8];
#pragma unroll
    for (int u = 0; u < 8; ++u) {
        ls[u] = vals[0][u] + vals[1][u] + vals[2][u] + vals[3][u];
        lq[u] = vals[0][u] * vals[0][u] + vals[1][u] * vals[1][u] +
                vals[2][u] * vals[2][u] + vals[3][u] * vals[3][u];
    }
    __syncthreads();
    int ca = 4 * tx, cb = 64 + 4 * tx;
#pragma unroll
    for (int u = 0; u < 4; ++u) {
        red[ty * 128 + ca + u] = ls[u];
        red[2048 + ty * 128 + ca + u] = lq[u];
        red[ty * 128 + cb + u] = ls[u + 4];
        red[2048 + ty * 128 + cb + u] = lq[u + 4];
    }
    __syncthreads();
    if (tid < 128) {
        float s = 0.f, q = 0.f;
#pragma unroll
        for (int t = 0; t < 16; ++t) {
            s += red[t * 128 + tid];
            q += red[2048 + t * 128 + tid];
        }
        atomicAdd(st + tid, s);
        atomicAdd(st + 128 + tid, q);
    }
}

// ---------------------------------------------------------------------------
// MFMA helpers (proven). A-frag LDS layout:
// Afr[((rt*4+kc)*64 + o*16 + m)*8 + j] = act[rt*16+m][kc*32+o*8+j] (fp16).
// Weights prepacked in GLOBAL: Wp[((ct*4+kc)*64+L)*8+j] =
// W[kc*32+(L>>4)*8+j][ct*16+(L&15)]. Wave w computes rows 0..63 x cols
// [32w, 32w+32). gemm2_gw: one weight-frag load feeds BOTH tiles' MFMAs.
// ---------------------------------------------------------------------------

__device__ __forceinline__ void gemm2_gw(const _Float16* A0, const _Float16* A1,
                                         const _Float16* __restrict__ wp,
                                         f4v acc0[4][2], f4v acc1[4][2], int lane, int w) {
#pragma unroll
    for (int kc = 0; kc < 4; ++kc) {
        h8 bf0 = *(const h8*)&wp[(((w * 2 + 0) * 4 + kc) * 64 + lane) * 8];
        h8 bf1 = *(const h8*)&wp[(((w * 2 + 1) * 4 + kc) * 64 + lane) * 8];
        h8 af0[4], af1[4];
#pragma unroll
        for (int rt = 0; rt < 4; ++rt) {
            af0[rt] = *(const h8*)&A0[((rt * 4 + kc) * 64 + lane) * 8];
            af1[rt] = *(const h8*)&A1[((rt * 4 + kc) * 64 + lane) * 8];
        }
#pragma unroll
        for (int rt = 0; rt < 4; ++rt) {
            acc0[rt][0] = __builtin_amdgcn_mfma_f32_16x16x32_f16(af0[rt], bf0, acc0[rt][0], 0, 0, 0);
            acc1[rt][0] = __builtin_amdgcn_mfma_f32_16x16x32_f16(af1[rt], bf0, acc1[rt][0], 0, 0, 0);
        }
#pragma unroll
        for (int rt = 0; rt < 4; ++rt) {
            acc0[rt][1] = __builtin_amdgcn_mfma_f32_16x16x32_f16(af0[rt], bf1, acc0[rt][1], 0, 0, 0);
            acc1[rt][1] = __builtin_amdgcn_mfma_f32_16x16x32_f16(af1[rt], bf1, acc1[rt][1], 0, 0, 0);
        }
    }
}

__device__ __forceinline__ void vals_to_afrag(_Float16* Afr, const float vals[4][2][4],
                                              int lane, int w) {
    int cl = lane & 15, quad = lane >> 4;
#pragma unroll
    for (int ctl = 0; ctl < 2; ++ctl) {
        int col = (w * 2 + ctl) * 16 + cl;
        int kc = col >> 5, o = (col >> 3) & 3, j = col & 7;
#pragma unroll
        for (int rt = 0; rt < 4; ++rt)
#pragma unroll
            for (int i = 0; i < 4; ++i) {
                int m = quad * 4 + i;
                Afr[((rt * 4 + kc) * 64 + o * 16 + m) * 8 + j] = (_Float16)vals[rt][ctl][i];
            }
    }
}

// stage A = elu(P[row] + Q[row] + bias) into A-frag layout (proven)
__device__ __forceinline__ void stage_pair(_Float16* Afr, const float4* __restrict__ Pr,
                                           const float4* __restrict__ Qr,
                                           const float4* __restrict__ B1, int lane, int kc) {
    int rt = lane >> 4, m = lane & 15;
#pragma unroll
    for (int o = 0; o < 4; ++o) {
        int c4 = kc * 8 + o * 2;
        float4 p0 = Pr[c4], q0 = Qr[c4], bb0 = B1[c4];
        float4 p1 = Pr[c4 + 1], q1 = Qr[c4 + 1], bb1 = B1[c4 + 1];
        h8 v;
        v[0] = (_Float16)elu_f(p0.x + q0.x + bb0.x);
        v[1] = (_Float16)elu_f(p0.y + q0.y + bb0.y);
        v[2] = (_Float16)elu_f(p0.z + q0.z + bb0.z);
        v[3] = (_Float16)elu_f(p0.w + q0.w + bb0.w);
        v[4] = (_Float16)elu_f(p1.x + q1.x + bb1.x);
        v[5] = (_Float16)elu_f(p1.y + q1.y + bb1.y);
        v[6] = (_Float16)elu_f(p1.z + q1.z + bb1.z);
        v[7] = (_Float16)elu_f(p1.w + q1.w + bb1.w);
        *(h8*)&Afr[((rt * 4 + kc) * 64 + o * 16 + m) * 8] = v;
    }
}

// ---------------------------------------------------------------------------
// Kernels
// ---------------------------------------------------------------------------

// merged: zero shadow-sum arenas + cvec; pack w2/w4 layer-2 weights to fp16 frag
__global__ void k_prep(float* W, const float* __restrict__ w2src,
                       const float* __restrict__ w4src) {
    int blk = blockIdx.x, tid = threadIdx.x;
    if (blk < 193) {
        int i = blk * 256 + tid;
        if (i < 16384) W[OFF_P2 + i] = 0.f;
        else if (i < 32768) W[OFF_P4 + i - 16384] = 0.f;
        else if (i < 49152) W[OFF_Q4 + i - 32768] = 0.f;
        else if (i < 49280) W[OFF_CVEC + i - 49152] = 0.f;
    } else {
        int second = blk >= 201;
        const float* src = second ? w4src : w2src;
        _Float16* wp = (_Float16*)(W + (second ? OFF_W4P : OFF_W2P));
        int flat = (blk - (second ? 201 : 193)) * 256 + tid;  // 0..2047
        int g = flat >> 6, L = flat & 63;
        int ct = g >> 2, kc = g & 3;
        int nn = ct * 16 + (L & 15), k0 = kc * 32 + (L >> 4) * 8;
        h8 v;
#pragma unroll
        for (int j = 0; j < 8; ++j) v[j] = (_Float16)src[(k0 + j) * 128 + nn];
        *(h8*)&wp[flat * 8] = v;
    }
}

__global__ void k_finalize(const float* __restrict__ sums, float* __restrict__ coef,
                           float invM, const float* __restrict__ g,
                           const float* __restrict__ beta, float* __restrict__ zbuf) {
    int c = threadIdx.x;  // 128
    float s = 0.f, q = 0.f;
#pragma unroll 8
    for (int t = 0; t < 64; ++t) {
        s += sums[t * 256 + c];
        q += sums[t * 256 + 128 + c];
    }
    float mean = s * invM;
    float var = q * invM - mean * mean;
    float a = g[c] * rsqrtf(var + BN_EPS);
    coef[c] = a;
    coef[128 + c] = beta[c] - mean * a;
    if (zbuf)
        for (int i = c; i < 16384; i += 128) zbuf[i] = 0.f;
}

// mlp1 (fp32, proven)
__global__ __launch_bounds__(256) void k_mlp1(const float* __restrict__ x,
                                              const float* __restrict__ w1,
                                              const float* __restrict__ b1,
                                              const float* __restrict__ w2,
                                              const float* __restrict__ b2,
                                              float* __restrict__ h1, float* __restrict__ st) {
    __shared__ float Xs[64 * 44];
    __shared__ float As[64 * 132];
    int tid = threadIdx.x, tx = tid & 15, ty = tid >> 4;
    int r0 = blockIdx.x * 64;
    for (int idx = tid; idx < 64 * 40; idx += 256) {
        int r = idx / 40, k = idx - r * 40;
        int rr = r0 + r, b = rr >> 6, n = rr & 63, t = k >> 2, d = k & 3;
        Xs[r * 44 + k] = x[((b * 10 + t) * 64 + n) * 4 + d];
    }
    __syncthreads();
    float acc[4][8] = {};
    gemm_globalW(Xs, 44, w1, 40, acc, tx, ty);
    float vals[4][8];
    bias_elu(acc, b1, vals, tx);
    int ca = 4 * tx, cb = 64 + 4 * tx;
#pragma unroll
    for (int j = 0; j < 4; ++j) {
        int r = ty + 16 * j;
#pragma unroll
        for (int u = 0; u < 4; ++u) {
            As[r * 132 + ca + u] = vals[j][u];
            As[r * 132 + cb + u] = vals[j][u + 4];
        }
    }
    __syncthreads();
    float acc2[4][8] = {};
    gemm_globalW(As, 132, w2, 128, acc2, tx, ty);
    float vals2[4][8];
    bias_elu(acc2, b2, vals2, tx);
    store_tile(h1, r0, vals2, tx, ty);
    stats_tail(vals2, As, st + (blockIdx.x & 63) * 256, tid, tx, ty);
}

// P/Q precompute (fp32), 32-row tiles for full-CU coverage. 256 blocks.
__global__ __launch_bounds__(256) void k_pq(const float* __restrict__ h,
                                            const float* __restrict__ coef,
                                            const float* __restrict__ w,
                                            float* __restrict__ P, float* __restrict__ Q) {
    __shared__ float As[32 * 132];
    int tid = threadIdx.x, tx = tid & 15, ty = tid >> 4;
    int half = blockIdx.x >> 7;
    int r0 = (blockIdx.x & 127) * 32;
    const float* Wg = w + half * 128 * 128;
    float* out = half ? Q : P;
    const float4* h4 = (const float4*)h;
    const float4* av = (const float4*)coef;
    const float4* cv = (const float4*)(coef + 128);
#pragma unroll
    for (int i = 0; i < 4; ++i) {
        int f4 = tid + i * 256;
        int r = f4 >> 5, c4 = f4 & 31;
        float4 hv = h4[(r0 + r) * 32 + c4];
        float4 a = av[c4], c = cv[c4];
        float4 v;
        v.x = a.x * hv.x + c.x;
        v.y = a.y * hv.y + c.y;
        v.z = a.z * hv.z + c.z;
        v.w = a.w * hv.w + c.w;
        *(float4*)(As + r * 132 + c4 * 4) = v;
    }
    __syncthreads();
    float acc[2][8] = {};
    const float4* Wg4 = (const float4*)Wg;
#pragma unroll 4
    for (int k = 0; k < 128; ++k) {
        float a0 = As[ty * 132 + k];
        float a1 = As[(ty + 16) * 132 + k];
        float4 wa = Wg4[k * 32 + tx];
        float4 wb = Wg4[k * 32 + 16 + tx];
        const float wv[8] = {wa.x, wa.y, wa.z, wa.w, wb.x, wb.y, wb.z, wb.w};
#pragma unroll
        for (int u = 0; u < 8; ++u) {
            acc[0][u] = fmaf(a0, wv[u], acc[0][u]);
            acc[1][u] = fmaf(a1, wv[u], acc[1][u]);
        }
    }
#pragma unroll
    for (int j = 0; j < 2; ++j) {
        int r = r0 + ty + 16 * j;
        *(float4*)(out + r * 128 + 4 * tx) = make_float4(acc[j][0], acc[j][1], acc[j][2], acc[j][3]);
        *(float4*)(out + r * 128 + 64 + 4 * tx) = make_float4(acc[j][4], acc[j][5], acc[j][6], acc[j][7]);
    }
}

// Recv-major fused mlp2 + edge2node + h2 materialization, TWO recv tiles per
// block (n0=2j, n1=2j+1) sharing weight fragments. 2048 blocks.
__global__ __launch_bounds__(256, 3) void k_mlp2agg(const float* __restrict__ P2,
                                                    const float* __restrict__ Q2,
                                                    const float* __restrict__ b1,
                                                    const _Float16* __restrict__ w2p,
                                                    const float* __restrict__ b2,
                                                    float* __restrict__ aggraw,
                                                    _Float16* __restrict__ h2,
                                                    float* __restrict__ st) {
    __shared__ _Float16 Afr0[8192];  // tile n0; reused as row-major bounce
    __shared__ _Float16 Afr1[8192];  // tile n1
    int tid = threadIdx.x;
    int lane = tid & 63, w = tid >> 6, cl = lane & 15, quad = lane >> 4;
    int b = blockIdx.x >> 5, j2 = blockIdx.x & 31;
    int n0 = 2 * j2, n1 = n0 + 1;
    float* stc = st + (blockIdx.x & 63) * 256;
    {
        int r = lane;
        int s0 = (r < 63) ? (r + (r >= n0 ? 1 : 0)) : n0;  // row 63: dummy
        int s1i = (r < 63) ? (r + (r >= n1 ? 1 : 0)) : n1;
        const float4* B1 = (const float4*)b1;
        stage_pair(Afr0, (const float4*)(P2 + (b * 64 + s0) * 128),
                   (const float4*)(Q2 + (b * 64 + n0) * 128), B1, lane, w);
        stage_pair(Afr1, (const float4*)(P2 + (b * 64 + s1i) * 128),
                   (const float4*)(Q2 + (b * 64 + n1) * 128), B1, lane, w);
    }
    __syncthreads();
    f4v acc0[4][2], acc1[4][2];
#pragma unroll
    for (int rt = 0; rt < 4; ++rt)
#pragma unroll
        for (int c = 0; c < 2; ++c) {
            acc0[rt][c] = (f4v){0.f, 0.f, 0.f, 0.f};
            acc1[rt][c] = (f4v){0.f, 0.f, 0.f, 0.f};
        }
    gemm2_gw(Afr0, Afr1, w2p, acc0, acc1, lane, w);
    // epilogue: bias+elu, mask dummy row 63, per-tile agg + merged stats
    float v0[2][4][4], v1[2][4][4];  // [ctl][rt][i]
#pragma unroll
    for (int ctl = 0; ctl < 2; ++ctl) {
        int col = (w * 2 + ctl) * 16 + cl;
        float bias = b2[col];
        float a0 = 0.f, a1 = 0.f, sq = 0.f;
#pragma unroll
        for (int rt = 0; rt < 4; ++rt)
#pragma unroll
            for (int i = 0; i < 4; ++i) {
                int row = rt * 16 + quad * 4 + i;
                float va = elu_f(acc0[rt][ctl][i] + bias);
                float vb = elu_f(acc1[rt][ctl][i] + bias);
                if (row == 63) { va = 0.f; vb = 0.f; }
                v0[ctl][rt][i] = va;
                v1[ctl][rt][i] = vb;
                a0 += va;
                a1 += vb;
                sq += va * va + vb * vb;
            }
        a0 += __shfl_xor(a0, 16);
        a1 += __shfl_xor(a1, 16);
        sq += __shfl_xor(sq, 16);
        a0 += __shfl_xor(a0, 32);
        a1 += __shfl_xor(a1, 32);
        sq += __shfl_xor(sq, 32);
        if (quad == 0) {
            aggraw[(b * 64 + n0) * 128 + col] = a0;
            aggraw[(b * 64 + n1) * 128 + col] = a1;
            atomicAdd(stc + col, a0 + a1);
            atomicAdd(stc + 128 + col, sq);
        }
    }
    __syncthreads();  // GEMM A-frag reads done; reuse Afr as row-major tiles
    unsigned short* T0 = (unsigned short*)Afr0;
    unsigned short* T1 = (unsigned short*)Afr1;
#pragma unroll
    for (int ctl = 0; ctl < 2; ++ctl) {
        int col = (w * 2 + ctl) * 16 + cl;
#pragma unroll
        for (int rt = 0; rt < 4; ++rt)
#pragma unroll
            for (int i = 0; i < 4; ++i) {
                int row = rt * 16 + quad * 4 + i;
                _Float16 ha = (_Float16)v0[ctl][rt][i];
                _Float16 hb = (_Float16)v1[ctl][rt][i];
                T0[row * 128 + col] = *(unsigned short*)&ha;
                T1[row * 128 + col] = *(unsigned short*)&hb;
            }
    }
    __syncthreads();
    {  // scatter 63 real rows per tile to h2[e], e = s*63 + (s>n ? n : n-1)
        int rr = tid >> 2, cq = tid & 3;
        if (rr < 63) {
            int s0 = rr + (rr >= n0 ? 1 : 0);
            int e0 = s0 * 63 + (s0 > n0 ? n0 : n0 - 1);
            int s1i = rr + (rr >= n1 ? 1 : 0);
            int e1 = s1i * 63 + (s1i > n1 ? n1 : n1 - 1);
            unsigned short* d0 = (unsigned short*)h2 + ((size_t)b * 4032 + e0) * 128;
            unsigned short* d1 = (unsigned short*)h2 + ((size_t)b * 4032 + e1) * 128;
#pragma unroll
            for (int i = 0; i < 4; ++i) {
                int off = cq * 32 + i * 8;
                *(uint4*)(d0 + off) = *(uint4*)&T0[rr * 128 + off];
                *(uint4*)(d1 + off) = *(uint4*)&T1[rr * 128 + off];
            }
        }
    }
}

// prep for mlp4 skip path (proven)
__global__ void k_wcprep(const float* __restrict__ w41, const float* __restrict__ coef2,
                         _Float16* __restrict__ wcp, float* __restrict__ cvec) {
    int k = blockIdx.x, c = threadIdx.x;  // 128 x 128
    float wv = w41[(256 + k) * 128 + c];
    int g = (c >> 4) * 4 + (k >> 5);
    int L = ((k >> 3) & 3) * 16 + (c & 15);
    int j = k & 7;
    wcp[(g * 64 + L) * 8 + j] = (_Float16)(coef2[k] * wv);
    atomicAdd(&cvec[c], coef2[128 + k] * wv);
}

// mlp3 (fp32, proven)
__global__ __launch_bounds__(256) void k_mlp3(const float* __restrict__ raw,
                                              const float* __restrict__ coef2,
                                              const float* __restrict__ w1,
                                              const float* __restrict__ b1,
                                              const float* __restrict__ w2,
                                              const float* __restrict__ b2,
                                              float* __restrict__ h3, float* __restrict__ st) {
    __shared__ float As[64 * 132];
    int tid = threadIdx.x, tx = tid & 15, ty = tid >> 4;
    int r0 = blockIdx.x * 64;
    const float4* in4 = (const float4*)raw;
    const float4* av = (const float4*)coef2;
    const float4* cv = (const float4*)(coef2 + 128);
    const float inv63 = 1.f / 63.f;
#pragma unroll
    for (int i = 0; i < 8; ++i) {
        int f4 = tid + i * 256;
        int r = f4 >> 5, c4 = f4 & 31;
        float4 hv = in4[(r0 + r) * 32 + c4];
        float4 a = av[c4], c = cv[c4];
        float4 v;
        v.x = a.x * hv.x * inv63 + c.x;
        v.y = a.y * hv.y * inv63 + c.y;
        v.z = a.z * hv.z * inv63 + c.z;
        v.w = a.w * hv.w * inv63 + c.w;
        *(float4*)(As + r * 132 + c4 * 4) = v;
    }
    __syncthreads();
    float acc[4][8] = {};
    gemm_globalW(As, 132, w1, 128, acc, tx, ty);
    float vals[4][8];
    bias_elu(acc, b1, vals, tx);
    __syncthreads();
    int ca = 4 * tx, cb = 64 + 4 * tx;
#pragma unroll
    for (int j = 0; j < 4; ++j) {
        int r = ty + 16 * j;
#pragma unroll
        for (int u = 0; u < 4; ++u) {
            As[r * 132 + ca + u] = vals[j][u];
            As[r * 132 + cb + u] = vals[j][u + 4];
        }
    }
    __syncthreads();
    float acc2[4][8] = {};
    gemm_globalW(As, 132, w2, 128, acc2, tx, ty);
    float vals2[4][8];
    bias_elu(acc2, b2, vals2, tx);
    store_tile(h3, r0, vals2, tx, ty);
    stats_tail(vals2, As, st + (blockIdx.x & 63) * 256, tid, tx, ty);
}

// mlp4 edge kernel v2: h2 READ (not recomputed), two tiles/block, fp16 h4.
// ep2: tile-level send resolution (s spans <=2 values per 64-edge tile) ->
// P4 terms become preload+select; Q4 gathers keep per-row rv.
__global__ __launch_bounds__(256, 3) void k_mlp4r2(const _Float16* __restrict__ h2,
                                                   const float* __restrict__ P4,
                                                   const float* __restrict__ Q4,
                                                   const _Float16* __restrict__ wcp,
                                                   const float* __restrict__ cvec,
                                                   const float* __restrict__ b1,
                                                   const _Float16* __restrict__ w4p2,
                                                   const float* __restrict__ b2,
                                                   unsigned short* __restrict__ h4,
                                                   float* __restrict__ st) {
    __shared__ _Float16 Afr0[8192];  // 16 KB (tile 0; reused as fp16 bounce)
    __shared__ _Float16 Afr1[8192];  // 16 KB (tile 1)
    int tid = threadIdx.x;
    int lane = tid & 63, w = tid >> 6, cl = lane & 15, quad = lane >> 4;
    unsigned t0 = 2u * blockIdx.x, t1 = t0 + 1u;
    unsigned b0 = t0 / 63, b1i = t1 / 63;
    unsigned e00 = (t0 - b0 * 63) * 64, e01 = (t1 - b1i * 63) * 64;
    int row00 = t0 * 64, row01 = t1 * 64;
    float* stc = st + (blockIdx.x & 63) * 256;
    // stage h2 tiles: coalesced h8 loads (row-major) -> A-frag LDS
#pragma unroll
    for (int i = 0; i < 4; ++i) {
        int u = tid + i * 256;  // 0..1023
        int r = u >> 4, cu = u & 15;
        int dst = (((r >> 4) * 4 + (cu >> 2)) * 64 + (cu & 3) * 16 + (r & 15)) * 8;
        *(h8*)&Afr0[dst] = *(const h8*)&h2[(size_t)(row00 + r) * 128 + cu * 8];
        *(h8*)&Afr1[dst] = *(const h8*)&h2[(size_t)(row01 + r) * 128 + cu * 8];
    }
    __syncthreads();
    f4v acc0[4][2], acc1[4][2];
#pragma unroll
    for (int rt = 0; rt < 4; ++rt)
#pragma unroll
        for (int c = 0; c < 2; ++c) {
            acc0[rt][c] = (f4v){0.f, 0.f, 0.f, 0.f};
            acc1[rt][c] = (f4v){0.f, 0.f, 0.f, 0.f};
        }
    gemm2_gw(Afr0, Afr1, wcp, acc0, acc1, lane, w);
    // ep2: pre1 = elu(acc + P4[s][col] + Q4[rv][col] + b1[col] + cvec[col]).
    // s spans at most {sA, sA+1} within a 64-edge tile -> select, no division.
    float v0[4][2][4], v1[4][2][4];
    {
        int col0 = w * 32 + cl, col1 = col0 + 16;
        float base0 = b1[col0] + cvec[col0];
        float base1 = b1[col1] + cvec[col1];
        unsigned sA0 = e00 / 63, sA1 = e01 / 63;
        unsigned baseE0 = sA0 * 63, baseE1 = sA1 * 63;
        unsigned eB0 = baseE0 + 63, eB1 = baseE1 + 63;
        unsigned sB0 = sA0 < 63u ? sA0 + 1u : sA0;
        unsigned sB1 = sA1 < 63u ? sA1 + 1u : sA1;
        const float* PA0 = P4 + (b0 * 64 + sA0) * 128;
        const float* PB0 = P4 + (b0 * 64 + sB0) * 128;
        const float* PA1 = P4 + (b1i * 64 + sA1) * 128;
        const float* PB1 = P4 + (b1i * 64 + sB1) * 128;
        float pA0c0 = PA0[col0], pA0c1 = PA0[col1];
        float pB0c0 = PB0[col0], pB0c1 = PB0[col1];
        float pA1c0 = PA1[col0], pA1c1 = PA1[col1];
        float pB1c0 = PB1[col0], pB1c1 = PB1[col1];
        const float* Qb0 = Q4 + (size_t)b0 * 64 * 128;
        const float* Qb1 = Q4 + (size_t)b1i * 64 * 128;
#pragma unroll
        for (int rt = 0; rt < 4; ++rt)
#pragma unroll
            for (int i = 0; i < 4; ++i) {
                int rr = rt * 16 + quad * 4 + i;
                {
                    unsigned e = e00 + rr;
                    bool hi = e >= eB0;
                    unsigned s = hi ? sB0 : sA0;
                    unsigned jj = e - (hi ? eB0 : baseE0);
                    unsigned rv = jj + (jj >= s ? 1u : 0u);
                    const float* Qr = Qb0 + rv * 128;
                    float p0 = hi ? pB0c0 : pA0c0, p1 = hi ? pB0c1 : pA0c1;
                    v0[rt][0][i] = elu_f(acc0[rt][0][i] + p0 + Qr[col0] + base0);
                    v0[rt][1][i] = elu_f(acc0[rt][1][i] + p1 + Qr[col1] + base1);
                }
                {
                    unsigned e = e01 + rr;
                    bool hi = e >= eB1;
                    unsigned s = hi ? sB1 : sA1;
                    unsigned jj = e - (hi ? eB1 : baseE1);
                    unsigned rv = jj + (jj >= s ? 1u : 0u);
                    const float* Qr = Qb1 + rv * 128;
                    float p0 = hi ? pB1c0 : pA1c0, p1 = hi ? pB1c1 : pA1c1;
                    v1[rt][0][i] = elu_f(acc1[rt][0][i] + p0 + Qr[col0] + base0);
                    v1[rt][1][i] = elu_f(acc1[rt][1][i] + p1 + Qr[col1] + base1);
                }
            }
    }
    __syncthreads();
    vals_to_afrag(Afr0, v0, lane, w);
    vals_to_afrag(Afr1, v1, lane, w);
    __syncthreads();
#pragma unroll
    for (int rt = 0; rt < 4; ++rt)
#pragma unroll
        for (int c = 0; c < 2; ++c) {
            acc0[rt][c] = (f4v){0.f, 0.f, 0.f, 0.f};
            acc1[rt][c] = (f4v){0.f, 0.f, 0.f, 0.f};
        }
    gemm2_gw(Afr0, Afr1, w4p2, acc0, acc1, lane, w);
    // ep3: h4 = elu(acc + b2[col]) both tiles; merged column stats
#pragma unroll
    for (int ctl = 0; ctl < 2; ++ctl) {
        int col = (w * 2 + ctl) * 16 + cl;
        float bias = b2[col];
        float s1 = 0.f, s2 = 0.f;
#pragma unroll
        for (int rt = 0; rt < 4; ++rt)
#pragma unroll
            for (int i = 0; i < 4; ++i) {
                float va = elu_f(acc0[rt][ctl][i] + bias);
                float vb = elu_f(acc1[rt][ctl][i] + bias);
                v0[rt][ctl][i] = va;
                v1[rt][ctl][i] = vb;
                s1 += va + vb;
                s2 += va * va + vb * vb;
            }
        s1 += __shfl_xor(s1, 16);
        s2 += __shfl_xor(s2, 16);
        s1 += __shfl_xor(s1, 32);
        s2 += __shfl_xor(s2, 32);
        if (quad == 0) {
            atomicAdd(stc + col, s1);
            atomicAdd(stc + 128 + col, s2);
        }
    }
    __syncthreads();  // GEMM3 A-frag reads done; reuse Afr as fp16 tiles
    unsigned short* T0 = (unsigned short*)Afr0;
    unsigned short* T1 = (unsigned short*)Afr1;
#pragma unroll
    for (int ctl = 0; ctl < 2; ++ctl) {
        int col = (w * 2 + ctl) * 16 + cl;
#pragma unroll
        for (int rt = 0; rt < 4; ++rt)
#pragma unroll
            for (int i = 0; i < 4; ++i) {
                int rr = rt * 16 + quad * 4 + i;
                _Float16 ha = (_Float16)v0[rt][ctl][i];
                _Float16 hb = (_Float16)v1[rt][ctl][i];
                T0[rr * 128 + col] = *(unsigned short*)&ha;
                T1[rr * 128 + col] = *(unsigned short*)&hb;
            }
    }
    __syncthreads();
    {
        int rr = tid >> 2, cq = tid & 3;
#pragma unroll
        for (int i = 0; i < 4; ++i) {
            int off = rr * 128 + cq * 32 + i * 8;
            *(uint4*)(h4 + (size_t)row00 * 128 + off) = *(uint4*)&T0[off];
            *(uint4*)(h4 + (size_t)row01 * 128 + off) = *(uint4*)&T1[off];
        }
    }
}

// final: out[row,k] = sum_c (a4[c]*h4[row,c]+shift4[c]) * fcw[c,k] + fcb[k]
// h4 is fp16.
__global__ __launch_bounds__(256) void k_out(const unsigned short* __restrict__ h4,
                                             const float* __restrict__ coef4,
                                             const float* __restrict__ fcw,
                                             const float* __restrict__ fcb,
                                             float* __restrict__ out) {
    int tid = threadIdx.x;
    int lane = tid & 31, rsub = tid >> 5;
    int row = blockIdx.x * 8 + rsub;
    h4v hv = ((const h4v*)(h4 + (size_t)row * 128))[lane];
    float x0 = (float)hv[0], x1 = (float)hv[1], x2 = (float)hv[2], x3 = (float)hv[3];
    float4 a = ((const float4*)coef4)[lane];
    float4 c = ((const float4*)(coef4 + 128))[lane];
    x0 = a.x * x0 + c.x;
    x1 = a.y * x1 + c.y;
    x2 = a.z * x2 + c.z;
    x3 = a.w * x3 + c.w;
    const float4* W = (const float4*)(fcw + lane * 8);
    float4 w01 = W[0], w23 = W[1];
    float s0 = x0 * w01.x + x1 * w01.z + x2 * w23.x + x3 * w23.z;
    float s1 = x0 * w01.y + x1 * w01.w + x2 * w23.y + x3 * w23.w;
#pragma unroll
    for (int off = 16; off > 0; off >>= 1) {
        s0 += __shfl_down(s0, off, 32);
        s1 += __shfl_down(s1, off, 32);
    }
    if (lane == 0) {
        out[row * 2] = s0 + fcb[0];
        out[row * 2 + 1] = s1 + fcb[1];
    }
}

// ---------------------------------------------------------------------------

extern "C" void kernel_launch(void* const* d_in, const int* in_sizes, int n_in,
                              void* d_out, int out_size, void* d_ws, size_t ws_size,
                              hipStream_t stream) {
    const float* x = (const float*)d_in[0];
    const float* m1_w1 = (const float*)d_in[1];
    const float* m1_b1 = (const float*)d_in[2];
    const float* m1_w2 = (const float*)d_in[3];
    const float* m1_b2 = (const float*)d_in[4];
    const float* m1_g = (const float*)d_in[5];
    const float* m1_be = (const float*)d_in[6];
    const float* m2_w1 = (const float*)d_in[7];
    const float* m2_b1 = (const float*)d_in[8];
    const float* m2_w2 = (const float*)d_in[9];
    const float* m2_b2 = (const float*)d_in[10];
    const float* m2_g = (const float*)d_in[11];
    const float* m2_be = (const float*)d_in[12];
    const float* m3_w1 = (const float*)d_in[13];
    const float* m3_b1 = (const float*)d_in[14];
    const float* m3_w2 = (const float*)d_in[15];
    const float* m3_b2 = (const float*)d_in[16];
    const float* m3_g = (const float*)d_in[17];
    const float* m3_be = (const float*)d_in[18];
    const float* m4_w1 = (const float*)d_in[19];
    const float* m4_b1 = (const float*)d_in[20];
    const float* m4_w2 = (const float*)d_in[21];
    const float* m4_b2 = (const float*)d_in[22];
    const float* m4_g = (const float*)d_in[23];
    const float* m4_be = (const float*)d_in[24];
    const float* fc_w = (const float*)d_in[25];
    const float* fc_b = (const float*)d_in[26];
    float* out = (float*)d_out;

    float* W = (float*)d_ws;
    float* coef1 = W + OFF_COEF;
    float* coef2 = W + OFF_COEF + 256;
    float* coef3 = W + OFF_COEF + 512;
    float* coef4 = W + OFF_COEF + 768;
    float* cvec = W + OFF_CVEC;
    float* h1 = W + OFF_H1;        // aliased: aggraw; sums4 = h1[0:16384)
    float* aggraw = h1;
    float* sums4 = h1;
    float* P2 = W + OFF_P2;        // sums1 = P2[0:16384)
    float* sums1 = P2;
    float* Q2 = W + OFF_Q2;
    float* h3 = W + OFF_H3;
    float* P4 = W + OFF_P4;        // sums2 = P4[0:16384)
    float* sums2 = P4;
    float* Q4 = W + OFF_Q4;        // sums3 = Q4[0:16384)
    float* sums3 = Q4;
    _Float16* w2p2 = (_Float16*)(W + OFF_W2P);
    _Float16* w4p2 = (_Float16*)(W + OFF_W4P);
    _Float16* wcp = (_Float16*)(W + OFF_WCP);
    _Float16* h2f = (_Float16*)(W + OFF_H4B);             // h2 (fp16), then
    unsigned short* h4b = (unsigned short*)(W + OFF_H4B); // h4 (fp16) in place

    if (ws_size < WS_BYTES) return;  // safe-fail diagnostic (no OOB fault)

    k_prep<<<209, 256, 0, stream>>>(W, m2_w2, m4_w2);
    k_mlp1<<<64, 256, 0, stream>>>(x, m1_w1, m1_b1, m1_w2, m1_b2, h1, sums1);
    k_finalize<<<1, 128, 0, stream>>>(sums1, coef1, 1.f / 4096.f, m1_g, m1_be, nullptr);
    k_pq<<<256, 256, 0, stream>>>(h1, coef1, m2_w1, P2, Q2);
    k_mlp2agg<<<2048, 256, 0, stream>>>(P2, Q2, m2_b1, w2p2, m2_b2, aggraw, h2f, sums2);
    k_finalize<<<1, 128, 0, stream>>>(sums2, coef2, 1.f / 258048.f, m2_g, m2_be, nullptr);
    k_wcprep<<<128, 128, 0, stream>>>(m4_w1, coef2, wcp, cvec);
    k_mlp3<<<64, 256, 0, stream>>>(aggraw, coef2, m3_w1, m3_b1, m3_w2, m3_b2, h3, sums3);
    k_finalize<<<1, 128, 0, stream>>>(sums3, coef3, 1.f / 4096.f, m3_g, m3_be, sums4);
    k_pq<<<256, 256, 0, stream>>>(h3, coef3, m4_w1, P4, Q4);
    k_mlp4r2<<<2016, 256, 0, stream>>>(h2f, P4, Q4, wcp, cvec, m4_b1, w4p2, m4_b2,
                                       h4b, sums4);
    k_finalize<<<1, 128, 0, stream>>>(sums4, coef4, 1.f / 258048.f, m4_g, m4_be, nullptr);
    k_out<<<32256, 256, 0, stream>>>(h4b, coef4, fc_w, fc_b, out);
}